// Round 13
// baseline (515.017 us; speedup 1.0000x reference)
//
#include <hip/hip_runtime.h>
#include <hip/hip_bf16.h>
#include <hip/hip_cooperative_groups.h>
#include <cstdint>
#include <cstddef>

namespace cg = cooperative_groups;

#define FIN      128
#define HGAT_H   4
#define HGAT_C   64
#define HGAT_HC  256
#define NGRAPHS  64
#define NACT     32
#define LOG2E    1.4426950408889634f
#define CSRB     256    // cooperative CSR grid

typedef unsigned int   uint32;
typedef unsigned short ushort_t;

using short8 = __attribute__((ext_vector_type(8))) short;
using u16x8  = __attribute__((ext_vector_type(8))) ushort_t;
using f32x4  = __attribute__((ext_vector_type(4))) float;
using f32x2  = __attribute__((ext_vector_type(2))) float;

__device__ __forceinline__ float bf2f(ushort_t u) {
    return __uint_as_float(((uint32)u) << 16);
}
__device__ __forceinline__ float bflo(uint32 q) {
    return __uint_as_float(q << 16);
}
__device__ __forceinline__ float bfhi(uint32 q) {
    return __uint_as_float(q & 0xFFFF0000u);
}
__device__ __forceinline__ ushort_t f2bf(float f) {
    __hip_bfloat16 h = __float2bfloat16(f);   // RNE
    return *reinterpret_cast<ushort_t*>(&h);
}

// ---------------------------------------------------------------------------
// Prep: weight transpose/casts + attention fold, one launch.
// attB[k][j] = sum_c W[k][h*64+c]*att[h][c], j = h*2 + (0:src|1:dst),
// stored transposed [16][K] with hi/lo bf16 split (rows 8..15 = residual).
// ---------------------------------------------------------------------------
__device__ __forceinline__ void att_fold_one(
    const float* __restrict__ W, const float* __restrict__ as,
    const float* __restrict__ ad, ushort_t* __restrict__ attBt,
    int K, int idx)
{
    const int k = idx >> 3, j = idx & 7;
    const int h = j >> 1;
    const float* av = (j & 1) ? ad : as;
    float s = 0.f;
#pragma unroll 8
    for (int c = 0; c < HGAT_C; ++c)
        s += W[(size_t)k * HGAT_HC + h * 64 + c] * av[h * 64 + c];
    const ushort_t hi = f2bf(s);
    const float    lo = s - bf2f(hi);
    attBt[(size_t)j * K + k]       = hi;
    attBt[(size_t)(j + 8) * K + k] = f2bf(lo);
}

__global__ __launch_bounds__(256) void prep_kernel(
    const float* __restrict__ W1, const float* __restrict__ W2,
    const float* __restrict__ as1, const float* __restrict__ ad1,
    const float* __restrict__ as2, const float* __restrict__ ad2,
    ushort_t* __restrict__ Wt1, ushort_t* __restrict__ Wt2,
    ushort_t* __restrict__ attBt1, ushort_t* __restrict__ attBt2)
{
    const int idx = blockIdx.x * 256 + threadIdx.x;
    const int n1 = FIN * HGAT_HC;
    const int n2 = HGAT_HC * HGAT_HC;
    if (idx < n1) {
        const int k = idx >> 8, c = idx & 255;
        Wt1[(size_t)c * FIN + k] = f2bf(W1[idx]);
    } else if (idx < n1 + n2) {
        const int j = idx - n1;
        const int k = j >> 8, c = j & 255;
        Wt2[(size_t)c * HGAT_HC + k] = f2bf(W2[j]);
    } else if (idx < n1 + n2 + FIN * 8) {
        att_fold_one(W1, as1, ad1, attBt1, FIN, idx - n1 - n2);
    } else if (idx < n1 + n2 + (FIN + HGAT_HC) * 8) {
        att_fold_one(W2, as2, ad2, attBt2, HGAT_HC, idx - n1 - n2 - FIN * 8);
    }
}

// ---------------------------------------------------------------------------
// Cooperative CSR build: zero deg -> count -> chunk sums -> scan(1 block)
// -> rowptr/cursor -> fill.  One launch, CSRB blocks x 256 (co-resident).
// Valid for N <= CSRB*256.
// ---------------------------------------------------------------------------
__global__ __launch_bounds__(256) void csr_coop_kernel(
    const int* __restrict__ ei, int* __restrict__ deg, int* __restrict__ bsum,
    int* __restrict__ rowptr, int* __restrict__ cursor,
    int* __restrict__ colsrc, int N, int E)
{
    cg::grid_group grid = cg::this_grid();
    const int t   = threadIdx.x;
    const int tid = blockIdx.x * 256 + t;
    const int nth = gridDim.x * 256;
    __shared__ int sm[256];

    // phase 1: zero deg
    for (int i = tid; i < N; i += nth) deg[i] = 0;
    __threadfence();
    grid.sync();

    // phase 2: count in-degrees
    for (int e = tid; e < E; e += nth) atomicAdd(&deg[ei[E + e]], 1);
    __threadfence();
    grid.sync();

    // phase 3: per-block chunk sums
    const int chunk = (N + gridDim.x - 1) / gridDim.x;   // <= 256
    const int idx0  = blockIdx.x * chunk;
    {
        const int v = (t < chunk && idx0 + t < N) ? deg[idx0 + t] : 0;
        sm[t] = v;
        __syncthreads();
#pragma unroll
        for (int off = 128; off; off >>= 1) {
            if (t < off) sm[t] += sm[t + off];
            __syncthreads();
        }
        if (t == 0) bsum[blockIdx.x] = sm[0];
    }
    __threadfence();
    grid.sync();

    // phase 4: block 0 exclusive-scans bsum
    if (blockIdx.x == 0) {
        const int v = (t < (int)gridDim.x) ? bsum[t] : 0;
        sm[t] = v;
        __syncthreads();
#pragma unroll
        for (int off = 1; off < 256; off <<= 1) {
            const int u = (t >= off) ? sm[t - off] : 0;
            __syncthreads();
            sm[t] += u;
            __syncthreads();
        }
        if (t < (int)gridDim.x) bsum[t] = sm[t] - v;
    }
    __threadfence();
    grid.sync();

    // phase 5: per-block chunk scan -> rowptr & cursor
    {
        const int idx = idx0 + t;
        const int v   = (t < chunk && idx < N) ? deg[idx] : 0;
        sm[t] = v;
        __syncthreads();
#pragma unroll
        for (int off = 1; off < 256; off <<= 1) {
            const int u = (t >= off) ? sm[t - off] : 0;
            __syncthreads();
            sm[t] += u;
            __syncthreads();
        }
        const int base = bsum[blockIdx.x];
        if (t < chunk && idx < N) {
            const int r = base + sm[t] - v;
            rowptr[idx] = r;
            cursor[idx] = r;
        }
        if (idx == N - 1) rowptr[N] = base + sm[t];
    }
    __threadfence();
    grid.sync();

    // phase 6: fill colsrc
    for (int e = tid; e < E; e += nth) {
        const int d   = ei[E + e];
        const int pos = atomicAdd(&cursor[d], 1);
        colsrc[pos] = ei[e];
    }
}

// ---------------------------------------------------------------------------
// MFMA GEMM + attention epilogue.  C[M,256] = A[M,K] @ Wt^T.
// Block = 64 rows, 4 waves. A frags in registers; per-head B panel in LDS
// (stride K+8) with register prefetch of the next head; attention dots via
// one extra MFMA on the hi/lo-split attBt tile + shfl_xor(8); C staged in
// LDS (stride 72) and copied out as coalesced u16x8 rows.
// mfma_f32_16x16x32_bf16 D map: col=lane&15, row=(lane>>4)*4+reg.
// ---------------------------------------------------------------------------
template <int K, bool AF32>
__global__ __launch_bounds__(256) void gemm_mfma_att_kernel(
    const void* __restrict__ Av, const ushort_t* __restrict__ Bt,
    const ushort_t* __restrict__ attBt, ushort_t* __restrict__ Cb,
    float* __restrict__ a_src, float* __restrict__ a_dst, int M)
{
    constexpr int KK   = K / 32;
    constexpr int NPF  = K / 32;
    constexpr int BSTR = K + 8;
    constexpr int CSTR = 72;
    __shared__ ushort_t Bs[64 * BSTR];
    __shared__ ushort_t AttS[16 * BSTR];
    __shared__ ushort_t Cs[64 * CSTR];

    const int t  = threadIdx.x;
    const int w  = t >> 6;
    const int l  = t & 63;
    const int lg = l >> 4;
    const int lr = l & 15;
    const int rowbase = blockIdx.x * 64 + w * 16;

    const int srow  = t & 63;
    const int cbase = (t >> 6) * (K / 4);

    // ---- A fragments (A read once from HBM)
    short8 af[KK];
    {
        const int arow = rowbase + lr;
        const int gr   = arow < M ? arow : M - 1;
        if (AF32) {
            const float* Ap = (const float*)Av + (size_t)gr * K;
#pragma unroll
            for (int kk = 0; kk < KK; ++kk) {
                const float4 v0 = *reinterpret_cast<const float4*>(Ap + kk * 32 + lg * 8);
                const float4 v1 = *reinterpret_cast<const float4*>(Ap + kk * 32 + lg * 8 + 4);
                short8 s;
                s[0] = (short)f2bf(v0.x); s[1] = (short)f2bf(v0.y);
                s[2] = (short)f2bf(v0.z); s[3] = (short)f2bf(v0.w);
                s[4] = (short)f2bf(v1.x); s[5] = (short)f2bf(v1.y);
                s[6] = (short)f2bf(v1.z); s[7] = (short)f2bf(v1.w);
                af[kk] = s;
            }
        } else {
            const ushort_t* Ap = (const ushort_t*)Av + (size_t)gr * K;
#pragma unroll
            for (int kk = 0; kk < KK; ++kk)
                af[kk] = *reinterpret_cast<const short8*>(Ap + kk * 32 + lg * 8);
        }
    }

    // ---- stage attBt tile + head-0 B panel
    {
        const int r  = t & 15;
        const int cb = (t >> 4) * (K / 16);
        const ushort_t* src = attBt + (size_t)r * K + cb;
        ushort_t*       dst = &AttS[r * BSTR + cb];
#pragma unroll
        for (int j = 0; j < K / 128; ++j)
            *reinterpret_cast<u16x8*>(dst + j * 8) =
                *reinterpret_cast<const u16x8*>(src + j * 8);
    }
    {
        const ushort_t* src = Bt + (size_t)srow * K + cbase;
        ushort_t*       dst = &Bs[srow * BSTR + cbase];
#pragma unroll
        for (int j = 0; j < NPF; ++j)
            *reinterpret_cast<u16x8*>(dst + j * 8) =
                *reinterpret_cast<const u16x8*>(src + j * 8);
    }
    __syncthreads();

    // ---- attention dots: one MFMA chain over the 16-col att tile
    {
        f32x4 aacc = {0.f, 0.f, 0.f, 0.f};
#pragma unroll
        for (int kk = 0; kk < KK; ++kk) {
            const short8 bfr = *reinterpret_cast<const short8*>(
                &AttS[lr * BSTR + kk * 32 + lg * 8]);
            aacc = __builtin_amdgcn_mfma_f32_16x16x32_bf16(af[kk], bfr, aacc, 0, 0, 0);
        }
#pragma unroll
        for (int reg = 0; reg < 4; ++reg) {
            const int gm = rowbase + lg * 4 + reg;
            const float v = aacc[reg] + __shfl_xor(aacc[reg], 8);   // hi + lo
            if (lr < 8 && gm < M) {
                const int hh = lr >> 1;
                if (lr & 1) a_dst[gm * 4 + hh] = v * LOG2E;
                else        a_src[gm * 4 + hh] = v * LOG2E;
            }
        }
    }

    // ---- head loop
    u16x8 pf[NPF];
#pragma unroll
    for (int head = 0; head < HGAT_H; ++head) {
        if (head < HGAT_H - 1) {
            const ushort_t* src =
                Bt + ((size_t)(head + 1) * 64 + srow) * K + cbase;
#pragma unroll
            for (int j = 0; j < NPF; ++j)
                pf[j] = *reinterpret_cast<const u16x8*>(src + j * 8);
        }

        f32x4 acc[4];
#pragma unroll
        for (int ct = 0; ct < 4; ++ct) acc[ct] = {0.f, 0.f, 0.f, 0.f};

#pragma unroll
        for (int kk = 0; kk < KK; ++kk) {
            short8 bfr[4];
#pragma unroll
            for (int ct = 0; ct < 4; ++ct)
                bfr[ct] = *reinterpret_cast<const short8*>(
                    &Bs[(ct * 16 + lr) * BSTR + kk * 32 + lg * 8]);
#pragma unroll
            for (int ct = 0; ct < 4; ++ct)
                acc[ct] = __builtin_amdgcn_mfma_f32_16x16x32_bf16(
                    af[kk], bfr[ct], acc[ct], 0, 0, 0);
        }

        // stage C tile (64x64 bf16) in LDS
#pragma unroll
        for (int reg = 0; reg < 4; ++reg) {
            const int r = w * 16 + lg * 4 + reg;
#pragma unroll
            for (int ct = 0; ct < 4; ++ct)
                Cs[r * CSTR + ct * 16 + lr] = f2bf(acc[ct][reg]);
        }
        __syncthreads();   // Cs complete; all Bs reads complete

        // coalesced copy-out: 8 threads/row, 16B each
        const int n0 = head * 64;
        {
            const int cc = (t & 7) * 8;
#pragma unroll
            for (int it = 0; it < 2; ++it) {
                const int r  = (t >> 3) + it * 32;
                const int gm = blockIdx.x * 64 + r;
                if (gm < M) {
                    const u16x8 val = *reinterpret_cast<const u16x8*>(&Cs[r * CSTR + cc]);
                    *reinterpret_cast<u16x8*>(&Cb[(size_t)gm * HGAT_HC + n0 + cc]) = val;
                }
            }
        }

        if (head < HGAT_H - 1) {   // commit prefetched panel
            ushort_t* dst = &Bs[srow * BSTR + cbase];
#pragma unroll
            for (int j = 0; j < NPF; ++j)
                *reinterpret_cast<u16x8*>(dst + j * 8) = pf[j];
        }
        __syncthreads();   // new Bs panel visible; Cs free for next head
    }
}

// ---------------------------------------------------------------------------
// CSR aggregate, wave per dst node: 8-wide edge unroll (gather MLP), then
// 4-wide, then scalar remainder. Pre-scaled logits -> single v_exp_f32.
// MODE 0: concat + bias + ELU -> bf16 out[N,256].
// MODE 1: head-mean + bias + ELU -> bf16 out[N,64].
// ---------------------------------------------------------------------------
template <int MODE>
__global__ __launch_bounds__(256) void aggregate_csr_kernel(
    const int* __restrict__ rowptr, const int* __restrict__ colsrc,
    const ushort_t* __restrict__ hb, const float* __restrict__ a_src,
    const float* __restrict__ a_dst, const float* __restrict__ bias,
    ushort_t* __restrict__ out, int N)
{
    const int d    = (blockIdx.x * 256 + threadIdx.x) >> 6;
    const int lane = threadIdx.x & 63;
    if (d >= N) return;
    const int h  = lane >> 4;
    const int c0 = lane * 4;
    const float ad = a_dst[d * 4 + h];

    f32x2 acc01 = {0.f, 0.f}, acc23 = {0.f, 0.f};
    float den = 0.f;

    const int beg = rowptr[d], end = rowptr[d + 1];
    int i = beg;
    for (; i + 8 <= end; i += 8) {
        int   sv[8];
        float av[8];
        uint2 qv[8];
#pragma unroll
        for (int j = 0; j < 8; ++j) sv[j] = colsrc[i + j];
#pragma unroll
        for (int j = 0; j < 8; ++j) av[j] = a_src[sv[j] * 4 + h];
#pragma unroll
        for (int j = 0; j < 8; ++j)
            qv[j] = *reinterpret_cast<const uint2*>(&hb[(size_t)sv[j] * HGAT_HC + c0]);
#pragma unroll
        for (int j = 0; j < 8; ++j) {
            float ee = av[j] + ad;
            ee = fmaxf(ee, 0.2f * ee);
            const float wgt = __builtin_amdgcn_exp2f(ee);
            const f32x2 w2 = {wgt, wgt};
            const f32x2 p01 = {bflo(qv[j].x), bfhi(qv[j].x)};
            const f32x2 p23 = {bflo(qv[j].y), bfhi(qv[j].y)};
            acc01 += w2 * p01;
            acc23 += w2 * p23;
            den += wgt;
        }
    }
    for (; i + 4 <= end; i += 4) {
        int   sv[4];
        float av[4];
        uint2 qv[4];
#pragma unroll
        for (int j = 0; j < 4; ++j) sv[j] = colsrc[i + j];
#pragma unroll
        for (int j = 0; j < 4; ++j) av[j] = a_src[sv[j] * 4 + h];
#pragma unroll
        for (int j = 0; j < 4; ++j)
            qv[j] = *reinterpret_cast<const uint2*>(&hb[(size_t)sv[j] * HGAT_HC + c0]);
#pragma unroll
        for (int j = 0; j < 4; ++j) {
            float ee = av[j] + ad;
            ee = fmaxf(ee, 0.2f * ee);
            const float wgt = __builtin_amdgcn_exp2f(ee);
            const f32x2 w2 = {wgt, wgt};
            const f32x2 p01 = {bflo(qv[j].x), bfhi(qv[j].x)};
            const f32x2 p23 = {bflo(qv[j].y), bfhi(qv[j].y)};
            acc01 += w2 * p01;
            acc23 += w2 * p23;
            den += wgt;
        }
    }
    for (; i < end; ++i) {
        const int s = colsrc[i];
        float ee = a_src[s * 4 + h] + ad;
        ee = fmaxf(ee, 0.2f * ee);
        const float wgt = __builtin_amdgcn_exp2f(ee);
        const uint2 q = *reinterpret_cast<const uint2*>(&hb[(size_t)s * HGAT_HC + c0]);
        const f32x2 w2 = {wgt, wgt};
        const f32x2 p01 = {bflo(q.x), bfhi(q.x)};
        const f32x2 p23 = {bflo(q.y), bfhi(q.y)};
        acc01 += w2 * p01;
        acc23 += w2 * p23;
        den += wgt;
    }
    {   // self loop
        float ee = a_src[d * 4 + h] + ad;
        ee = fmaxf(ee, 0.2f * ee);
        const float wgt = __builtin_amdgcn_exp2f(ee);
        const uint2 q = *reinterpret_cast<const uint2*>(&hb[(size_t)d * HGAT_HC + c0]);
        const f32x2 w2 = {wgt, wgt};
        const f32x2 p01 = {bflo(q.x), bfhi(q.x)};
        const f32x2 p23 = {bflo(q.y), bfhi(q.y)};
        acc01 += w2 * p01;
        acc23 += w2 * p23;
        den += wgt;
    }

    const float inv = 1.0f / den;
    float4 v = {acc01.x * inv, acc01.y * inv, acc23.x * inv, acc23.y * inv};

    if (MODE == 0) {
        v.x += bias[c0 + 0]; v.y += bias[c0 + 1];
        v.z += bias[c0 + 2]; v.w += bias[c0 + 3];
        v.x = v.x > 0.f ? v.x : expm1f(v.x);
        v.y = v.y > 0.f ? v.y : expm1f(v.y);
        v.z = v.z > 0.f ? v.z : expm1f(v.z);
        v.w = v.w > 0.f ? v.w : expm1f(v.w);
        ushort4 u;
        u.x = f2bf(v.x); u.y = f2bf(v.y); u.z = f2bf(v.z); u.w = f2bf(v.w);
        *reinterpret_cast<ushort4*>(&out[(size_t)d * HGAT_HC + c0]) = u;
    } else {
        v.x += __shfl_xor(v.x, 16); v.x += __shfl_xor(v.x, 32);
        v.y += __shfl_xor(v.y, 16); v.y += __shfl_xor(v.y, 32);
        v.z += __shfl_xor(v.z, 16); v.z += __shfl_xor(v.z, 32);
        v.w += __shfl_xor(v.w, 16); v.w += __shfl_xor(v.w, 32);
        if (lane < 16) {
            const int c = lane * 4;
            float4 r;
            r.x = 0.25f * v.x + bias[c + 0];
            r.y = 0.25f * v.y + bias[c + 1];
            r.z = 0.25f * v.z + bias[c + 2];
            r.w = 0.25f * v.w + bias[c + 3];
            r.x = r.x > 0.f ? r.x : expm1f(r.x);
            r.y = r.y > 0.f ? r.y : expm1f(r.y);
            r.z = r.z > 0.f ? r.z : expm1f(r.z);
            r.w = r.w > 0.f ? r.w : expm1f(r.w);
            ushort4 u;
            u.x = f2bf(r.x); u.y = f2bf(r.y); u.z = f2bf(r.z); u.w = f2bf(r.w);
            *reinterpret_cast<ushort4*>(&out[(size_t)d * HGAT_C + c]) = u;
        }
    }
}

// ---------------------------------------------------------------------------
// Pool stage A: 8 node-slices per graph -> partial sums.
// ---------------------------------------------------------------------------
__device__ __forceinline__ int lower_bound_batch(
    const int* __restrict__ batch, int N, int key)
{
    int lo = 0, hi = N;
    while (lo < hi) {
        const int mid = (lo + hi) >> 1;
        if (batch[mid] < key) lo = mid + 1; else hi = mid;
    }
    return lo;
}

__global__ __launch_bounds__(256) void pool_partial_kernel(
    const ushort_t* __restrict__ hfin, const int* __restrict__ batch,
    float* __restrict__ partial, int N)
{
    const int g   = blockIdx.x >> 3;
    const int s   = blockIdx.x & 7;
    const int t   = threadIdx.x;
    const int c   = t & 63;
    const int sub = t >> 6;

    const int beg = lower_bound_batch(batch, N, g);
    const int end = lower_bound_batch(batch, N, g + 1);
    const int len = end - beg;
    const int sl  = (len + 7) >> 3;
    const int sb  = beg + s * sl;
    const int se  = sb + sl < end ? sb + sl : end;

    float acc = 0.f;
    for (int n = sb + sub; n < se; n += 4)
        acc += bf2f(hfin[(size_t)n * HGAT_C + c]);

    __shared__ float sm[256];
    sm[t] = acc;
    __syncthreads();
    if (sub == 0)
        partial[(size_t)(g * 8 + s) * HGAT_C + c] =
            sm[c] + sm[64 + c] + sm[128 + c] + sm[192 + c];
}

// ---------------------------------------------------------------------------
// Pool stage B fused with final linear: one block per graph.
// ---------------------------------------------------------------------------
__global__ __launch_bounds__(64) void pool_final_fused_kernel(
    const float* __restrict__ partial, const int* __restrict__ batch,
    const float* __restrict__ Wa, const float* __restrict__ ba,
    float* __restrict__ out, int N)
{
    const int g = blockIdx.x;
    const int c = threadIdx.x;
    const int beg = lower_bound_batch(batch, N, g);
    const int end = lower_bound_batch(batch, N, g + 1);
    float s = 0.f;
#pragma unroll
    for (int k = 0; k < 8; ++k)
        s += partial[(size_t)(g * 8 + k) * HGAT_C + c];
    s /= fmaxf((float)(end - beg), 1.0f);

    __shared__ float pr[HGAT_C];
    pr[c] = s;
    __syncthreads();
    if (c < NACT) {
        float o = ba[c];
#pragma unroll
        for (int cc = 0; cc < HGAT_C; ++cc)
            o += pr[cc] * Wa[cc * NACT + c];
        out[g * NACT + c] = o;
    }
}

// ---------------------------------------------------------------------------
extern "C" void kernel_launch(void* const* d_in, const int* in_sizes, int n_in,
                              void* d_out, int out_size, void* d_ws, size_t ws_size,
                              hipStream_t stream)
{
    const float* x     = (const float*)d_in[0];
    const int*   ei    = (const int*)d_in[1];
    const int*   batch = (const int*)d_in[2];
    const float* W1    = (const float*)d_in[5];
    const float* as1   = (const float*)d_in[6];
    const float* ad1   = (const float*)d_in[7];
    const float* b1    = (const float*)d_in[8];
    const float* W2    = (const float*)d_in[9];
    const float* as2   = (const float*)d_in[10];
    const float* ad2   = (const float*)d_in[11];
    const float* b2    = (const float*)d_in[12];
    const float* Wa    = (const float*)d_in[13];
    const float* ba    = (const float*)d_in[14];

    const int N = in_sizes[0] / FIN;
    const int E = in_sizes[1] / 2;

    char* ws = (char*)d_ws;
    size_t off = 0;
    auto alloc = [&](size_t bytes) -> void* {
        void* p = ws + off;
        off += (bytes + 255) & ~(size_t)255;
        return p;
    };
    ushort_t* hb      = (ushort_t*)alloc((size_t)N * HGAT_HC * 2);
    ushort_t* hpost   = (ushort_t*)alloc((size_t)N * HGAT_HC * 2);
    ushort_t* Wt1     = (ushort_t*)alloc((size_t)FIN * HGAT_HC * 2);
    ushort_t* Wt2     = (ushort_t*)alloc((size_t)HGAT_HC * HGAT_HC * 2);
    ushort_t* attBt1  = (ushort_t*)alloc((size_t)16 * FIN * 2);
    ushort_t* attBt2  = (ushort_t*)alloc((size_t)16 * HGAT_HC * 2);
    float*    a_src   = (float*)alloc((size_t)N * 4 * 4);
    float*    a_dst   = (float*)alloc((size_t)N * 4 * 4);
    int*      rowptr  = (int*)alloc((size_t)(N + 1) * 4);
    int*      colsrc  = (int*)alloc((size_t)E * 4);
    int*      deg     = (int*)alloc((size_t)N * 4);
    int*      cursor  = (int*)alloc((size_t)N * 4);
    int*      bsum    = (int*)alloc(CSRB * 4);
    float*    partial = (float*)alloc((size_t)NGRAPHS * 8 * HGAT_C * 4);
    ushort_t* hfin    = hpost;
    (void)ws_size; (void)n_in; (void)out_size;

    const int gemmBlocks     = (N + 63) / 64;
    const int nodeWaveBlocks = (N + 3) / 4;

    // ---------------- CSR build: one cooperative launch ----------------
    {
        int n = N, e = E;
        void* args[] = {(void*)&ei, (void*)&deg, (void*)&bsum, (void*)&rowptr,
                        (void*)&cursor, (void*)&colsrc, (void*)&n, (void*)&e};
        hipLaunchCooperativeKernel((const void*)csr_coop_kernel,
                                   dim3(CSRB), dim3(256), args, 0, stream);
    }

    // ---------------- prep: weight transpose/cast + att fold ----------------
    {
        const int total = FIN * HGAT_HC + HGAT_HC * HGAT_HC + (FIN + HGAT_HC) * 8;
        prep_kernel<<<(total + 255) / 256, 256, 0, stream>>>(
            W1, W2, as1, ad1, as2, ad2, Wt1, Wt2, attBt1, attBt2);
    }

    // ---------------- layer 1 ----------------
    gemm_mfma_att_kernel<FIN, true><<<gemmBlocks, 256, 0, stream>>>(
        x, Wt1, attBt1, hb, a_src, a_dst, N);
    aggregate_csr_kernel<0><<<nodeWaveBlocks, 256, 0, stream>>>(
        rowptr, colsrc, hb, a_src, a_dst, b1, hpost, N);

    // ---------------- layer 2 ----------------
    gemm_mfma_att_kernel<HGAT_HC, false><<<gemmBlocks, 256, 0, stream>>>(
        hpost, Wt2, attBt2, hb, a_src, a_dst, N);
    aggregate_csr_kernel<1><<<nodeWaveBlocks, 256, 0, stream>>>(
        rowptr, colsrc, hb, a_src, a_dst, b2, hfin, N);

    // ---------------- pool + final ----------------
    pool_partial_kernel<<<NGRAPHS * 8, 256, 0, stream>>>(hfin, batch, partial, N);
    pool_final_fused_kernel<<<NGRAPHS, 64, 0, stream>>>(
        partial, batch, Wa, ba, (float*)d_out, N);
}

// Round 14
// 309.949 us; speedup vs baseline: 1.6616x; 1.6616x over previous
//
#include <hip/hip_runtime.h>
#include <hip/hip_bf16.h>
#include <cstdint>
#include <cstddef>

#define FIN      128
#define HGAT_H   4
#define HGAT_C   64
#define HGAT_HC  256
#define NGRAPHS  64
#define NACT     32
#define LOG2E    1.4426950408889634f

typedef unsigned int   uint32;
typedef unsigned short ushort_t;

using short8 = __attribute__((ext_vector_type(8))) short;
using u16x8  = __attribute__((ext_vector_type(8))) ushort_t;
using f32x4  = __attribute__((ext_vector_type(4))) float;
using f32x2  = __attribute__((ext_vector_type(2))) float;

__device__ __forceinline__ float bf2f(ushort_t u) {
    return __uint_as_float(((uint32)u) << 16);
}
__device__ __forceinline__ float bflo(uint32 q) {
    return __uint_as_float(q << 16);
}
__device__ __forceinline__ float bfhi(uint32 q) {
    return __uint_as_float(q & 0xFFFF0000u);
}
__device__ __forceinline__ ushort_t f2bf(float f) {
    __hip_bfloat16 h = __float2bfloat16(f);   // RNE
    return *reinterpret_cast<ushort_t*>(&h);
}

// ---------------------------------------------------------------------------
// Prep: weight transpose/casts + attention fold, one launch.
// attB[k][j] = sum_c W[k][h*64+c]*att[h][c], j = h*2 + (0:src|1:dst),
// stored transposed [16][K] with hi/lo bf16 split (rows 8..15 = residual).
// ---------------------------------------------------------------------------
__device__ __forceinline__ void att_fold_one(
    const float* __restrict__ W, const float* __restrict__ as,
    const float* __restrict__ ad, ushort_t* __restrict__ attBt,
    int K, int idx)
{
    const int k = idx >> 3, j = idx & 7;
    const int h = j >> 1;
    const float* av = (j & 1) ? ad : as;
    float s = 0.f;
#pragma unroll 8
    for (int c = 0; c < HGAT_C; ++c)
        s += W[(size_t)k * HGAT_HC + h * 64 + c] * av[h * 64 + c];
    const ushort_t hi = f2bf(s);
    const float    lo = s - bf2f(hi);
    attBt[(size_t)j * K + k]       = hi;
    attBt[(size_t)(j + 8) * K + k] = f2bf(lo);
}

__global__ __launch_bounds__(256) void prep_kernel(
    const float* __restrict__ W1, const float* __restrict__ W2,
    const float* __restrict__ as1, const float* __restrict__ ad1,
    const float* __restrict__ as2, const float* __restrict__ ad2,
    ushort_t* __restrict__ Wt1, ushort_t* __restrict__ Wt2,
    ushort_t* __restrict__ attBt1, ushort_t* __restrict__ attBt2)
{
    const int idx = blockIdx.x * 256 + threadIdx.x;
    const int n1 = FIN * HGAT_HC;
    const int n2 = HGAT_HC * HGAT_HC;
    if (idx < n1) {
        const int k = idx >> 8, c = idx & 255;
        Wt1[(size_t)c * FIN + k] = f2bf(W1[idx]);
    } else if (idx < n1 + n2) {
        const int j = idx - n1;
        const int k = j >> 8, c = j & 255;
        Wt2[(size_t)c * HGAT_HC + k] = f2bf(W2[j]);
    } else if (idx < n1 + n2 + FIN * 8) {
        att_fold_one(W1, as1, ad1, attBt1, FIN, idx - n1 - n2);
    } else if (idx < n1 + n2 + (FIN + HGAT_HC) * 8) {
        att_fold_one(W2, as2, ad2, attBt2, HGAT_HC, idx - n1 - n2 - FIN * 8);
    }
}

// ---------------------------------------------------------------------------
// CSR build: degree count, hierarchical 3-launch scan, cursor fill.
// (separate kernels -- cooperative grid.sync measured 10x slower, r13)
// ---------------------------------------------------------------------------
__global__ __launch_bounds__(256) void count_deg_kernel(
    const int* __restrict__ ei, int* __restrict__ deg, int E)
{
    const int e = blockIdx.x * 256 + threadIdx.x;
    if (e < E) atomicAdd(&deg[ei[E + e]], 1);
}

__global__ __launch_bounds__(256) void block_sum_kernel(
    const int* __restrict__ deg, int* __restrict__ bsum, int N)
{
    __shared__ int sm[256];
    const int idx = blockIdx.x * 256 + threadIdx.x;
    sm[threadIdx.x] = idx < N ? deg[idx] : 0;
    __syncthreads();
#pragma unroll
    for (int off = 128; off; off >>= 1) {
        if (threadIdx.x < off) sm[threadIdx.x] += sm[threadIdx.x + off];
        __syncthreads();
    }
    if (threadIdx.x == 0) bsum[blockIdx.x] = sm[0];
}

__global__ __launch_bounds__(256) void scan_bsums_kernel(
    int* __restrict__ bsum, int NB)
{
    __shared__ int sm[256];
    const int t = threadIdx.x;
    int v = t < NB ? bsum[t] : 0;
    sm[t] = v;
    __syncthreads();
#pragma unroll
    for (int off = 1; off < 256; off <<= 1) {
        const int u = (t >= off) ? sm[t - off] : 0;
        __syncthreads();
        sm[t] += u;
        __syncthreads();
    }
    if (t < NB) bsum[t] = sm[t] - v;   // exclusive
}

__global__ __launch_bounds__(256) void rowptr_kernel(
    const int* __restrict__ deg, const int* __restrict__ bsum,
    int* __restrict__ rowptr, int* __restrict__ cursor, int N)
{
    __shared__ int sm[256];
    const int t   = threadIdx.x;
    const int idx = blockIdx.x * 256 + t;
    const int v   = idx < N ? deg[idx] : 0;
    sm[t] = v;
    __syncthreads();
#pragma unroll
    for (int off = 1; off < 256; off <<= 1) {
        const int u = (t >= off) ? sm[t - off] : 0;
        __syncthreads();
        sm[t] += u;
        __syncthreads();
    }
    const int base = bsum[blockIdx.x];
    if (idx < N) {
        const int r = base + sm[t] - v;
        rowptr[idx] = r;
        cursor[idx] = r;
    }
    if (idx == N - 1) rowptr[N] = base + sm[t];
}

__global__ __launch_bounds__(256) void fill_csr_kernel(
    const int* __restrict__ ei, int* __restrict__ cursor,
    int* __restrict__ colsrc, int E)
{
    const int e = blockIdx.x * 256 + threadIdx.x;
    if (e >= E) return;
    const int d = ei[E + e];
    const int pos = atomicAdd(&cursor[d], 1);
    colsrc[pos] = ei[e];
}

// ---------------------------------------------------------------------------
// MFMA GEMM + attention epilogue.  C[M,256] = A[M,K] @ Wt^T.
// Block = 64 rows, 4 waves. A frags in registers; per-head B panel in LDS
// (stride K+8) with register prefetch of the next head; attention dots via
// one extra MFMA on the hi/lo-split attBt tile + shfl_xor(8); C staged in
// LDS (stride 72) and copied out as coalesced u16x8 rows.
// mfma_f32_16x16x32_bf16 D map: col=lane&15, row=(lane>>4)*4+reg.
// ---------------------------------------------------------------------------
template <int K, bool AF32>
__global__ __launch_bounds__(256) void gemm_mfma_att_kernel(
    const void* __restrict__ Av, const ushort_t* __restrict__ Bt,
    const ushort_t* __restrict__ attBt, ushort_t* __restrict__ Cb,
    float* __restrict__ a_src, float* __restrict__ a_dst, int M)
{
    constexpr int KK   = K / 32;
    constexpr int NPF  = K / 32;
    constexpr int BSTR = K + 8;
    constexpr int CSTR = 72;
    __shared__ ushort_t Bs[64 * BSTR];
    __shared__ ushort_t AttS[16 * BSTR];
    __shared__ ushort_t Cs[64 * CSTR];

    const int t  = threadIdx.x;
    const int w  = t >> 6;
    const int l  = t & 63;
    const int lg = l >> 4;
    const int lr = l & 15;
    const int rowbase = blockIdx.x * 64 + w * 16;

    const int srow  = t & 63;
    const int cbase = (t >> 6) * (K / 4);

    // ---- A fragments (A read once from HBM)
    short8 af[KK];
    {
        const int arow = rowbase + lr;
        const int gr   = arow < M ? arow : M - 1;
        if (AF32) {
            const float* Ap = (const float*)Av + (size_t)gr * K;
#pragma unroll
            for (int kk = 0; kk < KK; ++kk) {
                const float4 v0 = *reinterpret_cast<const float4*>(Ap + kk * 32 + lg * 8);
                const float4 v1 = *reinterpret_cast<const float4*>(Ap + kk * 32 + lg * 8 + 4);
                short8 s;
                s[0] = (short)f2bf(v0.x); s[1] = (short)f2bf(v0.y);
                s[2] = (short)f2bf(v0.z); s[3] = (short)f2bf(v0.w);
                s[4] = (short)f2bf(v1.x); s[5] = (short)f2bf(v1.y);
                s[6] = (short)f2bf(v1.z); s[7] = (short)f2bf(v1.w);
                af[kk] = s;
            }
        } else {
            const ushort_t* Ap = (const ushort_t*)Av + (size_t)gr * K;
#pragma unroll
            for (int kk = 0; kk < KK; ++kk)
                af[kk] = *reinterpret_cast<const short8*>(Ap + kk * 32 + lg * 8);
        }
    }

    // ---- stage attBt tile + head-0 B panel
    {
        const int r  = t & 15;
        const int cb = (t >> 4) * (K / 16);
        const ushort_t* src = attBt + (size_t)r * K + cb;
        ushort_t*       dst = &AttS[r * BSTR + cb];
#pragma unroll
        for (int j = 0; j < K / 128; ++j)
            *reinterpret_cast<u16x8*>(dst + j * 8) =
                *reinterpret_cast<const u16x8*>(src + j * 8);
    }
    {
        const ushort_t* src = Bt + (size_t)srow * K + cbase;
        ushort_t*       dst = &Bs[srow * BSTR + cbase];
#pragma unroll
        for (int j = 0; j < NPF; ++j)
            *reinterpret_cast<u16x8*>(dst + j * 8) =
                *reinterpret_cast<const u16x8*>(src + j * 8);
    }
    __syncthreads();

    // ---- attention dots: one MFMA chain over the 16-col att tile
    {
        f32x4 aacc = {0.f, 0.f, 0.f, 0.f};
#pragma unroll
        for (int kk = 0; kk < KK; ++kk) {
            const short8 bfr = *reinterpret_cast<const short8*>(
                &AttS[lr * BSTR + kk * 32 + lg * 8]);
            aacc = __builtin_amdgcn_mfma_f32_16x16x32_bf16(af[kk], bfr, aacc, 0, 0, 0);
        }
#pragma unroll
        for (int reg = 0; reg < 4; ++reg) {
            const int gm = rowbase + lg * 4 + reg;
            const float v = aacc[reg] + __shfl_xor(aacc[reg], 8);   // hi + lo
            if (lr < 8 && gm < M) {
                const int hh = lr >> 1;
                if (lr & 1) a_dst[gm * 4 + hh] = v * LOG2E;
                else        a_src[gm * 4 + hh] = v * LOG2E;
            }
        }
    }

    // ---- head loop
    u16x8 pf[NPF];
#pragma unroll
    for (int head = 0; head < HGAT_H; ++head) {
        if (head < HGAT_H - 1) {
            const ushort_t* src =
                Bt + ((size_t)(head + 1) * 64 + srow) * K + cbase;
#pragma unroll
            for (int j = 0; j < NPF; ++j)
                pf[j] = *reinterpret_cast<const u16x8*>(src + j * 8);
        }

        f32x4 acc[4];
#pragma unroll
        for (int ct = 0; ct < 4; ++ct) acc[ct] = {0.f, 0.f, 0.f, 0.f};

#pragma unroll
        for (int kk = 0; kk < KK; ++kk) {
            short8 bfr[4];
#pragma unroll
            for (int ct = 0; ct < 4; ++ct)
                bfr[ct] = *reinterpret_cast<const short8*>(
                    &Bs[(ct * 16 + lr) * BSTR + kk * 32 + lg * 8]);
#pragma unroll
            for (int ct = 0; ct < 4; ++ct)
                acc[ct] = __builtin_amdgcn_mfma_f32_16x16x32_bf16(
                    af[kk], bfr[ct], acc[ct], 0, 0, 0);
        }

        // stage C tile (64x64 bf16) in LDS
#pragma unroll
        for (int reg = 0; reg < 4; ++reg) {
            const int r = w * 16 + lg * 4 + reg;
#pragma unroll
            for (int ct = 0; ct < 4; ++ct)
                Cs[r * CSTR + ct * 16 + lr] = f2bf(acc[ct][reg]);
        }
        __syncthreads();   // Cs complete; all Bs reads complete

        // coalesced copy-out: 8 threads/row, 16B each
        const int n0 = head * 64;
        {
            const int cc = (t & 7) * 8;
#pragma unroll
            for (int it = 0; it < 2; ++it) {
                const int r  = (t >> 3) + it * 32;
                const int gm = blockIdx.x * 64 + r;
                if (gm < M) {
                    const u16x8 val = *reinterpret_cast<const u16x8*>(&Cs[r * CSTR + cc]);
                    *reinterpret_cast<u16x8*>(&Cb[(size_t)gm * HGAT_HC + n0 + cc]) = val;
                }
            }
        }

        if (head < HGAT_H - 1) {   // commit prefetched panel
            ushort_t* dst = &Bs[srow * BSTR + cbase];
#pragma unroll
            for (int j = 0; j < NPF; ++j)
                *reinterpret_cast<u16x8*>(dst + j * 8) = pf[j];
        }
        __syncthreads();   // new Bs panel visible; Cs free for next head
    }
}

// ---------------------------------------------------------------------------
// CSR aggregate, TWO nodes per wave: lanes 0-31 own node 2w, lanes 32-63
// own node 2w+1; each lane covers 8 channels via one uint4 (16B) gather.
// Halves waves, VMEM instructions, and per-edge VALU vs 1-node/wave.
// 4-wide edge unroll. Pre-scaled logits -> single v_exp_f32 per edge.
// MODE 0: concat + bias + ELU -> bf16 out[N,256].
// MODE 1: head-mean + bias + ELU -> bf16 out[N,64] (shfl_xor 8,16 within half).
// ---------------------------------------------------------------------------
template <int MODE>
__global__ __launch_bounds__(256) void aggregate_csr_kernel(
    const int* __restrict__ rowptr, const int* __restrict__ colsrc,
    const ushort_t* __restrict__ hb, const float* __restrict__ a_src,
    const float* __restrict__ a_dst, const float* __restrict__ bias,
    ushort_t* __restrict__ out, int N)
{
    const int wave = (blockIdx.x * 256 + threadIdx.x) >> 6;
    const int lane = threadIdx.x & 63;
    const int half = lane >> 5;
    const int hl   = lane & 31;
    const int d    = wave * 2 + half;
    if (d >= N) return;

    const int c0 = hl * 8;     // channel base (0..248)
    const int h  = hl >> 3;    // head 0..3
    const float ad = a_dst[d * 4 + h];

    f32x2 a01 = {0.f, 0.f}, a23 = {0.f, 0.f}, a45 = {0.f, 0.f}, a67 = {0.f, 0.f};
    float den = 0.f;

    const int beg = rowptr[d], end = rowptr[d + 1];
    int i = beg;
    for (; i + 4 <= end; i += 4) {
        int   sv[4];
        float av[4];
        uint4 qv[4];
#pragma unroll
        for (int j = 0; j < 4; ++j) sv[j] = colsrc[i + j];
#pragma unroll
        for (int j = 0; j < 4; ++j) av[j] = a_src[sv[j] * 4 + h];
#pragma unroll
        for (int j = 0; j < 4; ++j)
            qv[j] = *reinterpret_cast<const uint4*>(&hb[(size_t)sv[j] * HGAT_HC + c0]);
#pragma unroll
        for (int j = 0; j < 4; ++j) {
            float ee = av[j] + ad;
            ee = fmaxf(ee, 0.2f * ee);
            const float wgt = __builtin_amdgcn_exp2f(ee);
            const f32x2 w2 = {wgt, wgt};
            a01 += w2 * f32x2{bflo(qv[j].x), bfhi(qv[j].x)};
            a23 += w2 * f32x2{bflo(qv[j].y), bfhi(qv[j].y)};
            a45 += w2 * f32x2{bflo(qv[j].z), bfhi(qv[j].z)};
            a67 += w2 * f32x2{bflo(qv[j].w), bfhi(qv[j].w)};
            den += wgt;
        }
    }
    for (; i < end; ++i) {
        const int s = colsrc[i];
        float ee = a_src[s * 4 + h] + ad;
        ee = fmaxf(ee, 0.2f * ee);
        const float wgt = __builtin_amdgcn_exp2f(ee);
        const uint4 q = *reinterpret_cast<const uint4*>(&hb[(size_t)s * HGAT_HC + c0]);
        const f32x2 w2 = {wgt, wgt};
        a01 += w2 * f32x2{bflo(q.x), bfhi(q.x)};
        a23 += w2 * f32x2{bflo(q.y), bfhi(q.y)};
        a45 += w2 * f32x2{bflo(q.z), bfhi(q.z)};
        a67 += w2 * f32x2{bflo(q.w), bfhi(q.w)};
        den += wgt;
    }
    {   // self loop
        float ee = a_src[d * 4 + h] + ad;
        ee = fmaxf(ee, 0.2f * ee);
        const float wgt = __builtin_amdgcn_exp2f(ee);
        const uint4 q = *reinterpret_cast<const uint4*>(&hb[(size_t)d * HGAT_HC + c0]);
        const f32x2 w2 = {wgt, wgt};
        a01 += w2 * f32x2{bflo(q.x), bfhi(q.x)};
        a23 += w2 * f32x2{bflo(q.y), bfhi(q.y)};
        a45 += w2 * f32x2{bflo(q.z), bfhi(q.z)};
        a67 += w2 * f32x2{bflo(q.w), bfhi(q.w)};
        den += wgt;
    }

    const float inv = 1.0f / den;
    float v[8] = {a01.x * inv, a01.y * inv, a23.x * inv, a23.y * inv,
                  a45.x * inv, a45.y * inv, a67.x * inv, a67.y * inv};

    if (MODE == 0) {
        const float4 b0 = *reinterpret_cast<const float4*>(&bias[c0]);
        const float4 b1 = *reinterpret_cast<const float4*>(&bias[c0 + 4]);
        v[0] += b0.x; v[1] += b0.y; v[2] += b0.z; v[3] += b0.w;
        v[4] += b1.x; v[5] += b1.y; v[6] += b1.z; v[7] += b1.w;
        u16x8 u;
#pragma unroll
        for (int j = 0; j < 8; ++j) {
            const float r = v[j] > 0.f ? v[j] : expm1f(v[j]);
            u[j] = f2bf(r);
        }
        *reinterpret_cast<u16x8*>(&out[(size_t)d * HGAT_HC + c0]) = u;
    } else {
        // head reduce within the 32-lane half: lanes hl, hl^8, hl^16 hold
        // the same (channel mod 64) set
#pragma unroll
        for (int j = 0; j < 8; ++j) {
            v[j] += __shfl_xor(v[j], 8);
            v[j] += __shfl_xor(v[j], 16);
        }
        if (hl < 8) {
            const int c = hl * 8;   // channel base in [0,64)
            const float4 b0 = *reinterpret_cast<const float4*>(&bias[c]);
            const float4 b1 = *reinterpret_cast<const float4*>(&bias[c + 4]);
            const float bb[8] = {b0.x, b0.y, b0.z, b0.w, b1.x, b1.y, b1.z, b1.w};
            u16x8 u;
#pragma unroll
            for (int j = 0; j < 8; ++j) {
                float r = 0.25f * v[j] + bb[j];
                r = r > 0.f ? r : expm1f(r);
                u[j] = f2bf(r);
            }
            *reinterpret_cast<u16x8*>(&out[(size_t)d * HGAT_C + c]) = u;
        }
    }
}

// ---------------------------------------------------------------------------
// Pool stage A: 8 node-slices per graph -> partial sums.
// ---------------------------------------------------------------------------
__device__ __forceinline__ int lower_bound_batch(
    const int* __restrict__ batch, int N, int key)
{
    int lo = 0, hi = N;
    while (lo < hi) {
        const int mid = (lo + hi) >> 1;
        if (batch[mid] < key) lo = mid + 1; else hi = mid;
    }
    return lo;
}

__global__ __launch_bounds__(256) void pool_partial_kernel(
    const ushort_t* __restrict__ hfin, const int* __restrict__ batch,
    float* __restrict__ partial, int N)
{
    const int g   = blockIdx.x >> 3;
    const int s   = blockIdx.x & 7;
    const int t   = threadIdx.x;
    const int c   = t & 63;
    const int sub = t >> 6;

    const int beg = lower_bound_batch(batch, N, g);
    const int end = lower_bound_batch(batch, N, g + 1);
    const int len = end - beg;
    const int sl  = (len + 7) >> 3;
    const int sb  = beg + s * sl;
    const int se  = sb + sl < end ? sb + sl : end;

    float acc = 0.f;
    for (int n = sb + sub; n < se; n += 4)
        acc += bf2f(hfin[(size_t)n * HGAT_C + c]);

    __shared__ float sm[256];
    sm[t] = acc;
    __syncthreads();
    if (sub == 0)
        partial[(size_t)(g * 8 + s) * HGAT_C + c] =
            sm[c] + sm[64 + c] + sm[128 + c] + sm[192 + c];
}

// ---------------------------------------------------------------------------
// Pool stage B fused with final linear: one block per graph.
// ---------------------------------------------------------------------------
__global__ __launch_bounds__(64) void pool_final_fused_kernel(
    const float* __restrict__ partial, const int* __restrict__ batch,
    const float* __restrict__ Wa, const float* __restrict__ ba,
    float* __restrict__ out, int N)
{
    const int g = blockIdx.x;
    const int c = threadIdx.x;
    const int beg = lower_bound_batch(batch, N, g);
    const int end = lower_bound_batch(batch, N, g + 1);
    float s = 0.f;
#pragma unroll
    for (int k = 0; k < 8; ++k)
        s += partial[(size_t)(g * 8 + k) * HGAT_C + c];
    s /= fmaxf((float)(end - beg), 1.0f);

    __shared__ float pr[HGAT_C];
    pr[c] = s;
    __syncthreads();
    if (c < NACT) {
        float o = ba[c];
#pragma unroll
        for (int cc = 0; cc < HGAT_C; ++cc)
            o += pr[cc] * Wa[cc * NACT + c];
        out[g * NACT + c] = o;
    }
}

// ---------------------------------------------------------------------------
extern "C" void kernel_launch(void* const* d_in, const int* in_sizes, int n_in,
                              void* d_out, int out_size, void* d_ws, size_t ws_size,
                              hipStream_t stream)
{
    const float* x     = (const float*)d_in[0];
    const int*   ei    = (const int*)d_in[1];
    const int*   batch = (const int*)d_in[2];
    const float* W1    = (const float*)d_in[5];
    const float* as1   = (const float*)d_in[6];
    const float* ad1   = (const float*)d_in[7];
    const float* b1    = (const float*)d_in[8];
    const float* W2    = (const float*)d_in[9];
    const float* as2   = (const float*)d_in[10];
    const float* ad2   = (const float*)d_in[11];
    const float* b2    = (const float*)d_in[12];
    const float* Wa    = (const float*)d_in[13];
    const float* ba    = (const float*)d_in[14];

    const int N = in_sizes[0] / FIN;
    const int E = in_sizes[1] / 2;

    char* ws = (char*)d_ws;
    size_t off = 0;
    auto alloc = [&](size_t bytes) -> void* {
        void* p = ws + off;
        off += (bytes + 255) & ~(size_t)255;
        return p;
    };
    ushort_t* hb      = (ushort_t*)alloc((size_t)N * HGAT_HC * 2);
    ushort_t* hpost   = (ushort_t*)alloc((size_t)N * HGAT_HC * 2);
    ushort_t* Wt1     = (ushort_t*)alloc((size_t)FIN * HGAT_HC * 2);
    ushort_t* Wt2     = (ushort_t*)alloc((size_t)HGAT_HC * HGAT_HC * 2);
    ushort_t* attBt1  = (ushort_t*)alloc((size_t)16 * FIN * 2);
    ushort_t* attBt2  = (ushort_t*)alloc((size_t)16 * HGAT_HC * 2);
    float*    a_src   = (float*)alloc((size_t)N * 4 * 4);
    float*    a_dst   = (float*)alloc((size_t)N * 4 * 4);
    int*      rowptr  = (int*)alloc((size_t)(N + 1) * 4);
    int*      colsrc  = (int*)alloc((size_t)E * 4);
    int*      deg     = (int*)alloc((size_t)N * 4);
    int*      cursor  = (int*)alloc((size_t)N * 4);
    int*      bsum    = (int*)alloc(256 * 4);
    float*    partial = (float*)alloc((size_t)NGRAPHS * 8 * HGAT_C * 4);
    ushort_t* hfin    = hpost;
    (void)ws_size; (void)n_in; (void)out_size;

    const int gemmBlocks     = (N + 63) / 64;
    const int edgeBlocks     = (E + 255) / 256;
    const int aggBlocks      = (N + 7) / 8;     // 2 nodes/wave, 4 waves/block
    const int NB             = (N + 255) / 256;

    // ---------------- CSR build (separate kernels) ----------------
    hipMemsetAsync(deg, 0, (size_t)N * 4, stream);
    count_deg_kernel<<<edgeBlocks, 256, 0, stream>>>(ei, deg, E);
    block_sum_kernel<<<NB, 256, 0, stream>>>(deg, bsum, N);
    scan_bsums_kernel<<<1, 256, 0, stream>>>(bsum, NB);
    rowptr_kernel<<<NB, 256, 0, stream>>>(deg, bsum, rowptr, cursor, N);
    fill_csr_kernel<<<edgeBlocks, 256, 0, stream>>>(ei, cursor, colsrc, E);

    // ---------------- prep: weight transpose/cast + att fold ----------------
    {
        const int total = FIN * HGAT_HC + HGAT_HC * HGAT_HC + (FIN + HGAT_HC) * 8;
        prep_kernel<<<(total + 255) / 256, 256, 0, stream>>>(
            W1, W2, as1, ad1, as2, ad2, Wt1, Wt2, attBt1, attBt2);
    }

    // ---------------- layer 1 ----------------
    gemm_mfma_att_kernel<FIN, true><<<gemmBlocks, 256, 0, stream>>>(
        x, Wt1, attBt1, hb, a_src, a_dst, N);
    aggregate_csr_kernel<0><<<aggBlocks, 256, 0, stream>>>(
        rowptr, colsrc, hb, a_src, a_dst, b1, hpost, N);

    // ---------------- layer 2 ----------------
    gemm_mfma_att_kernel<HGAT_HC, false><<<gemmBlocks, 256, 0, stream>>>(
        hpost, Wt2, attBt2, hb, a_src, a_dst, N);
    aggregate_csr_kernel<1><<<aggBlocks, 256, 0, stream>>>(
        rowptr, colsrc, hb, a_src, a_dst, b2, hfin, N);

    // ---------------- pool + final ----------------
    pool_partial_kernel<<<NGRAPHS * 8, 256, 0, stream>>>(hfin, batch, partial, N);
    pool_final_fused_kernel<<<NGRAPHS, 64, 0, stream>>>(
        partial, batch, Wa, ba, (float*)d_out, N);
}

// Round 15
// 309.288 us; speedup vs baseline: 1.6652x; 1.0021x over previous
//
#include <hip/hip_runtime.h>
#include <hip/hip_bf16.h>
#include <cstdint>
#include <cstddef>

#define FIN      128
#define HGAT_H   4
#define HGAT_C   64
#define HGAT_HC  256
#define NGRAPHS  64
#define NACT     32
#define LOG2E    1.4426950408889634f

typedef unsigned int   uint32;
typedef unsigned short ushort_t;

using short8 = __attribute__((ext_vector_type(8))) short;
using u16x8  = __attribute__((ext_vector_type(8))) ushort_t;
using f32x4  = __attribute__((ext_vector_type(4))) float;
using f32x2  = __attribute__((ext_vector_type(2))) float;

__device__ __forceinline__ float bf2f(ushort_t u) {
    return __uint_as_float(((uint32)u) << 16);
}
__device__ __forceinline__ float bflo(uint32 q) {
    return __uint_as_float(q << 16);
}
__device__ __forceinline__ float bfhi(uint32 q) {
    return __uint_as_float(q & 0xFFFF0000u);
}
__device__ __forceinline__ ushort_t f2bf(float f) {
    __hip_bfloat16 h = __float2bfloat16(f);   // RNE
    return *reinterpret_cast<ushort_t*>(&h);
}

// ---------------------------------------------------------------------------
// attB fold helper: attB[k][j] = sum_c W[k][h*64+c]*att[h][c],
// j = h*2 + (0:src|1:dst); stored transposed [16][K] with hi/lo bf16 split.
// ---------------------------------------------------------------------------
__device__ __forceinline__ void att_fold_one(
    const float* __restrict__ W, const float* __restrict__ as,
    const float* __restrict__ ad, ushort_t* __restrict__ attBt,
    int K, int idx)
{
    const int k = idx >> 3, j = idx & 7;
    const int h = j >> 1;
    const float* av = (j & 1) ? ad : as;
    float s = 0.f;
#pragma unroll 8
    for (int c = 0; c < HGAT_C; ++c)
        s += W[(size_t)k * HGAT_HC + h * 64 + c] * av[h * 64 + c];
    const ushort_t hi = f2bf(s);
    const float    lo = s - bf2f(hi);
    attBt[(size_t)j * K + k]       = hi;
    attBt[(size_t)(j + 8) * K + k] = f2bf(lo);
}

// ---------------------------------------------------------------------------
// Merged: in-degree count (edges) + weight transpose/cast + att fold.
// gid < E            -> count one edge
// gid - E < prepTot  -> prep element
// ---------------------------------------------------------------------------
__global__ __launch_bounds__(256) void count_prep_kernel(
    const int* __restrict__ ei, int* __restrict__ deg,
    const float* __restrict__ W1, const float* __restrict__ W2,
    const float* __restrict__ as1, const float* __restrict__ ad1,
    const float* __restrict__ as2, const float* __restrict__ ad2,
    ushort_t* __restrict__ Wt1, ushort_t* __restrict__ Wt2,
    ushort_t* __restrict__ attBt1, ushort_t* __restrict__ attBt2, int E)
{
    const int gid = blockIdx.x * 256 + threadIdx.x;
    if (gid < E) {
        atomicAdd(&deg[ei[E + gid]], 1);
        return;
    }
    const int idx = gid - E;
    const int n1 = FIN * HGAT_HC;
    const int n2 = HGAT_HC * HGAT_HC;
    if (idx < n1) {
        const int k = idx >> 8, c = idx & 255;
        Wt1[(size_t)c * FIN + k] = f2bf(W1[idx]);
    } else if (idx < n1 + n2) {
        const int j = idx - n1;
        const int k = j >> 8, c = j & 255;
        Wt2[(size_t)c * HGAT_HC + k] = f2bf(W2[j]);
    } else if (idx < n1 + n2 + FIN * 8) {
        att_fold_one(W1, as1, ad1, attBt1, FIN, idx - n1 - n2);
    } else if (idx < n1 + n2 + (FIN + HGAT_HC) * 8) {
        att_fold_one(W2, as2, ad2, attBt2, HGAT_HC, idx - n1 - n2 - FIN * 8);
    }
}

// ---------------------------------------------------------------------------
// Hierarchical scan (3 small launches) + nt-store fill.
// ---------------------------------------------------------------------------
__global__ __launch_bounds__(256) void block_sum_kernel(
    const int* __restrict__ deg, int* __restrict__ bsum, int N)
{
    __shared__ int sm[256];
    const int idx = blockIdx.x * 256 + threadIdx.x;
    sm[threadIdx.x] = idx < N ? deg[idx] : 0;
    __syncthreads();
#pragma unroll
    for (int off = 128; off; off >>= 1) {
        if (threadIdx.x < off) sm[threadIdx.x] += sm[threadIdx.x + off];
        __syncthreads();
    }
    if (threadIdx.x == 0) bsum[blockIdx.x] = sm[0];
}

__global__ __launch_bounds__(256) void scan_bsums_kernel(
    int* __restrict__ bsum, int NB)
{
    __shared__ int sm[256];
    const int t = threadIdx.x;
    int v = t < NB ? bsum[t] : 0;
    sm[t] = v;
    __syncthreads();
#pragma unroll
    for (int off = 1; off < 256; off <<= 1) {
        const int u = (t >= off) ? sm[t - off] : 0;
        __syncthreads();
        sm[t] += u;
        __syncthreads();
    }
    if (t < NB) bsum[t] = sm[t] - v;   // exclusive
}

__global__ __launch_bounds__(256) void rowptr_kernel(
    const int* __restrict__ deg, const int* __restrict__ bsum,
    int* __restrict__ rowptr, int* __restrict__ cursor, int N)
{
    __shared__ int sm[256];
    const int t   = threadIdx.x;
    const int idx = blockIdx.x * 256 + t;
    const int v   = idx < N ? deg[idx] : 0;
    sm[t] = v;
    __syncthreads();
#pragma unroll
    for (int off = 1; off < 256; off <<= 1) {
        const int u = (t >= off) ? sm[t - off] : 0;
        __syncthreads();
        sm[t] += u;
        __syncthreads();
    }
    const int base = bsum[blockIdx.x];
    if (idx < N) {
        const int r = base + sm[t] - v;
        rowptr[idx] = r;
        cursor[idx] = r;
    }
    if (idx == N - 1) rowptr[N] = base + sm[t];
}

// fill with NONTEMPORAL colsrc stores: 4B scatters bypass L2 (no 64B
// write-allocate, no cross-XCD line thrash -- r14 showed 16x write amp).
// 2 edges per thread via int2 loads.
__global__ __launch_bounds__(256) void fill_csr_kernel(
    const int* __restrict__ ei, int* __restrict__ cursor,
    int* __restrict__ colsrc, int E)
{
    const int e0 = (blockIdx.x * 256 + threadIdx.x) * 2;
    if (e0 + 1 < E) {
        const int2 s2 = *reinterpret_cast<const int2*>(&ei[e0]);
        const int2 d2 = *reinterpret_cast<const int2*>(&ei[E + e0]);
        const int p0 = atomicAdd(&cursor[d2.x], 1);
        const int p1 = atomicAdd(&cursor[d2.y], 1);
        __builtin_nontemporal_store(s2.x, &colsrc[p0]);
        __builtin_nontemporal_store(s2.y, &colsrc[p1]);
    } else if (e0 < E) {
        const int s = ei[e0];
        const int d = ei[E + e0];
        const int p = atomicAdd(&cursor[d], 1);
        __builtin_nontemporal_store(s, &colsrc[p]);
    }
}

// ---------------------------------------------------------------------------
// MFMA GEMM + attention epilogue.  C[M,256] = A[M,K] @ Wt^T.
// Block = 64 rows, 4 waves. A frags in registers; per-head B panel in LDS
// (stride K+8) with register prefetch of the next head; attention dots via
// one extra MFMA on the hi/lo-split attBt tile + shfl_xor(8); C staged in
// LDS (stride 72) and copied out as coalesced u16x8 rows.
// mfma_f32_16x16x32_bf16 D map: col=lane&15, row=(lane>>4)*4+reg.
// ---------------------------------------------------------------------------
template <int K, bool AF32>
__global__ __launch_bounds__(256) void gemm_mfma_att_kernel(
    const void* __restrict__ Av, const ushort_t* __restrict__ Bt,
    const ushort_t* __restrict__ attBt, ushort_t* __restrict__ Cb,
    float* __restrict__ a_src, float* __restrict__ a_dst, int M)
{
    constexpr int KK   = K / 32;
    constexpr int NPF  = K / 32;
    constexpr int BSTR = K + 8;
    constexpr int CSTR = 72;
    __shared__ ushort_t Bs[64 * BSTR];
    __shared__ ushort_t AttS[16 * BSTR];
    __shared__ ushort_t Cs[64 * CSTR];

    const int t  = threadIdx.x;
    const int w  = t >> 6;
    const int l  = t & 63;
    const int lg = l >> 4;
    const int lr = l & 15;
    const int rowbase = blockIdx.x * 64 + w * 16;

    const int srow  = t & 63;
    const int cbase = (t >> 6) * (K / 4);

    // ---- A fragments (A read once from HBM)
    short8 af[KK];
    {
        const int arow = rowbase + lr;
        const int gr   = arow < M ? arow : M - 1;
        if (AF32) {
            const float* Ap = (const float*)Av + (size_t)gr * K;
#pragma unroll
            for (int kk = 0; kk < KK; ++kk) {
                const float4 v0 = *reinterpret_cast<const float4*>(Ap + kk * 32 + lg * 8);
                const float4 v1 = *reinterpret_cast<const float4*>(Ap + kk * 32 + lg * 8 + 4);
                short8 s;
                s[0] = (short)f2bf(v0.x); s[1] = (short)f2bf(v0.y);
                s[2] = (short)f2bf(v0.z); s[3] = (short)f2bf(v0.w);
                s[4] = (short)f2bf(v1.x); s[5] = (short)f2bf(v1.y);
                s[6] = (short)f2bf(v1.z); s[7] = (short)f2bf(v1.w);
                af[kk] = s;
            }
        } else {
            const ushort_t* Ap = (const ushort_t*)Av + (size_t)gr * K;
#pragma unroll
            for (int kk = 0; kk < KK; ++kk)
                af[kk] = *reinterpret_cast<const short8*>(Ap + kk * 32 + lg * 8);
        }
    }

    // ---- stage attBt tile + head-0 B panel
    {
        const int r  = t & 15;
        const int cb = (t >> 4) * (K / 16);
        const ushort_t* src = attBt + (size_t)r * K + cb;
        ushort_t*       dst = &AttS[r * BSTR + cb];
#pragma unroll
        for (int j = 0; j < K / 128; ++j)
            *reinterpret_cast<u16x8*>(dst + j * 8) =
                *reinterpret_cast<const u16x8*>(src + j * 8);
    }
    {
        const ushort_t* src = Bt + (size_t)srow * K + cbase;
        ushort_t*       dst = &Bs[srow * BSTR + cbase];
#pragma unroll
        for (int j = 0; j < NPF; ++j)
            *reinterpret_cast<u16x8*>(dst + j * 8) =
                *reinterpret_cast<const u16x8*>(src + j * 8);
    }
    __syncthreads();

    // ---- attention dots: one MFMA chain over the 16-col att tile
    {
        f32x4 aacc = {0.f, 0.f, 0.f, 0.f};
#pragma unroll
        for (int kk = 0; kk < KK; ++kk) {
            const short8 bfr = *reinterpret_cast<const short8*>(
                &AttS[lr * BSTR + kk * 32 + lg * 8]);
            aacc = __builtin_amdgcn_mfma_f32_16x16x32_bf16(af[kk], bfr, aacc, 0, 0, 0);
        }
#pragma unroll
        for (int reg = 0; reg < 4; ++reg) {
            const int gm = rowbase + lg * 4 + reg;
            const float v = aacc[reg] + __shfl_xor(aacc[reg], 8);   // hi + lo
            if (lr < 8 && gm < M) {
                const int hh = lr >> 1;
                if (lr & 1) a_dst[gm * 4 + hh] = v * LOG2E;
                else        a_src[gm * 4 + hh] = v * LOG2E;
            }
        }
    }

    // ---- head loop
    u16x8 pf[NPF];
#pragma unroll
    for (int head = 0; head < HGAT_H; ++head) {
        if (head < HGAT_H - 1) {
            const ushort_t* src =
                Bt + ((size_t)(head + 1) * 64 + srow) * K + cbase;
#pragma unroll
            for (int j = 0; j < NPF; ++j)
                pf[j] = *reinterpret_cast<const u16x8*>(src + j * 8);
        }

        f32x4 acc[4];
#pragma unroll
        for (int ct = 0; ct < 4; ++ct) acc[ct] = {0.f, 0.f, 0.f, 0.f};

#pragma unroll
        for (int kk = 0; kk < KK; ++kk) {
            short8 bfr[4];
#pragma unroll
            for (int ct = 0; ct < 4; ++ct)
                bfr[ct] = *reinterpret_cast<const short8*>(
                    &Bs[(ct * 16 + lr) * BSTR + kk * 32 + lg * 8]);
#pragma unroll
            for (int ct = 0; ct < 4; ++ct)
                acc[ct] = __builtin_amdgcn_mfma_f32_16x16x32_bf16(
                    af[kk], bfr[ct], acc[ct], 0, 0, 0);
        }

        // stage C tile (64x64 bf16) in LDS
#pragma unroll
        for (int reg = 0; reg < 4; ++reg) {
            const int r = w * 16 + lg * 4 + reg;
#pragma unroll
            for (int ct = 0; ct < 4; ++ct)
                Cs[r * CSTR + ct * 16 + lr] = f2bf(acc[ct][reg]);
        }
        __syncthreads();   // Cs complete; all Bs reads complete

        // coalesced copy-out: 8 threads/row, 16B each
        const int n0 = head * 64;
        {
            const int cc = (t & 7) * 8;
#pragma unroll
            for (int it = 0; it < 2; ++it) {
                const int r  = (t >> 3) + it * 32;
                const int gm = blockIdx.x * 64 + r;
                if (gm < M) {
                    const u16x8 val = *reinterpret_cast<const u16x8*>(&Cs[r * CSTR + cc]);
                    *reinterpret_cast<u16x8*>(&Cb[(size_t)gm * HGAT_HC + n0 + cc]) = val;
                }
            }
        }

        if (head < HGAT_H - 1) {   // commit prefetched panel
            ushort_t* dst = &Bs[srow * BSTR + cbase];
#pragma unroll
            for (int j = 0; j < NPF; ++j)
                *reinterpret_cast<u16x8*>(dst + j * 8) = pf[j];
        }
        __syncthreads();   // new Bs panel visible; Cs free for next head
    }
}

// ---------------------------------------------------------------------------
// CSR aggregate, TWO nodes per wave: lanes 0-31 own node 2w, lanes 32-63
// own node 2w+1; each lane covers 8 channels via one uint4 (16B) gather.
// 4-wide edge unroll. Pre-scaled logits -> single v_exp_f32 per edge.
// MODE 0: concat + bias + ELU -> bf16 out[N,256].
// MODE 1: head-mean + bias + ELU -> bf16 out[N,64] (shfl_xor 8,16 in half).
// ---------------------------------------------------------------------------
template <int MODE>
__global__ __launch_bounds__(256) void aggregate_csr_kernel(
    const int* __restrict__ rowptr, const int* __restrict__ colsrc,
    const ushort_t* __restrict__ hb, const float* __restrict__ a_src,
    const float* __restrict__ a_dst, const float* __restrict__ bias,
    ushort_t* __restrict__ out, int N)
{
    const int wave = (blockIdx.x * 256 + threadIdx.x) >> 6;
    const int lane = threadIdx.x & 63;
    const int half = lane >> 5;
    const int hl   = lane & 31;
    const int d    = wave * 2 + half;
    if (d >= N) return;

    const int c0 = hl * 8;     // channel base (0..248)
    const int h  = hl >> 3;    // head 0..3
    const float ad = a_dst[d * 4 + h];

    f32x2 a01 = {0.f, 0.f}, a23 = {0.f, 0.f}, a45 = {0.f, 0.f}, a67 = {0.f, 0.f};
    float den = 0.f;

    const int beg = rowptr[d], end = rowptr[d + 1];
    int i = beg;
    for (; i + 4 <= end; i += 4) {
        int   sv[4];
        float av[4];
        uint4 qv[4];
#pragma unroll
        for (int j = 0; j < 4; ++j) sv[j] = colsrc[i + j];
#pragma unroll
        for (int j = 0; j < 4; ++j) av[j] = a_src[sv[j] * 4 + h];
#pragma unroll
        for (int j = 0; j < 4; ++j)
            qv[j] = *reinterpret_cast<const uint4*>(&hb[(size_t)sv[j] * HGAT_HC + c0]);
#pragma unroll
        for (int j = 0; j < 4; ++j) {
            float ee = av[j] + ad;
            ee = fmaxf(ee, 0.2f * ee);
            const float wgt = __builtin_amdgcn_exp2f(ee);
            const f32x2 w2 = {wgt, wgt};
            a01 += w2 * f32x2{bflo(qv[j].x), bfhi(qv[j].x)};
            a23 += w2 * f32x2{bflo(qv[j].y), bfhi(qv[j].y)};
            a45 += w2 * f32x2{bflo(qv[j].z), bfhi(qv[j].z)};
            a67 += w2 * f32x2{bflo(qv[j].w), bfhi(qv[j].w)};
            den += wgt;
        }
    }
    for (; i < end; ++i) {
        const int s = colsrc[i];
        float ee = a_src[s * 4 + h] + ad;
        ee = fmaxf(ee, 0.2f * ee);
        const float wgt = __builtin_amdgcn_exp2f(ee);
        const uint4 q = *reinterpret_cast<const uint4*>(&hb[(size_t)s * HGAT_HC + c0]);
        const f32x2 w2 = {wgt, wgt};
        a01 += w2 * f32x2{bflo(q.x), bfhi(q.x)};
        a23 += w2 * f32x2{bflo(q.y), bfhi(q.y)};
        a45 += w2 * f32x2{bflo(q.z), bfhi(q.z)};
        a67 += w2 * f32x2{bflo(q.w), bfhi(q.w)};
        den += wgt;
    }
    {   // self loop
        float ee = a_src[d * 4 + h] + ad;
        ee = fmaxf(ee, 0.2f * ee);
        const float wgt = __builtin_amdgcn_exp2f(ee);
        const uint4 q = *reinterpret_cast<const uint4*>(&hb[(size_t)d * HGAT_HC + c0]);
        const f32x2 w2 = {wgt, wgt};
        a01 += w2 * f32x2{bflo(q.x), bfhi(q.x)};
        a23 += w2 * f32x2{bflo(q.y), bfhi(q.y)};
        a45 += w2 * f32x2{bflo(q.z), bfhi(q.z)};
        a67 += w2 * f32x2{bflo(q.w), bfhi(q.w)};
        den += wgt;
    }

    const float inv = 1.0f / den;
    float v[8] = {a01.x * inv, a01.y * inv, a23.x * inv, a23.y * inv,
                  a45.x * inv, a45.y * inv, a67.x * inv, a67.y * inv};

    if (MODE == 0) {
        const float4 b0 = *reinterpret_cast<const float4*>(&bias[c0]);
        const float4 b1 = *reinterpret_cast<const float4*>(&bias[c0 + 4]);
        v[0] += b0.x; v[1] += b0.y; v[2] += b0.z; v[3] += b0.w;
        v[4] += b1.x; v[5] += b1.y; v[6] += b1.z; v[7] += b1.w;
        u16x8 u;
#pragma unroll
        for (int j = 0; j < 8; ++j) {
            const float r = v[j] > 0.f ? v[j] : expm1f(v[j]);
            u[j] = f2bf(r);
        }
        *reinterpret_cast<u16x8*>(&out[(size_t)d * HGAT_HC + c0]) = u;
    } else {
#pragma unroll
        for (int j = 0; j < 8; ++j) {
            v[j] += __shfl_xor(v[j], 8);
            v[j] += __shfl_xor(v[j], 16);
        }
        if (hl < 8) {
            const int c = hl * 8;
            const float4 b0 = *reinterpret_cast<const float4*>(&bias[c]);
            const float4 b1 = *reinterpret_cast<const float4*>(&bias[c + 4]);
            const float bb[8] = {b0.x, b0.y, b0.z, b0.w, b1.x, b1.y, b1.z, b1.w};
            u16x8 u;
#pragma unroll
            for (int j = 0; j < 8; ++j) {
                float r = 0.25f * v[j] + bb[j];
                r = r > 0.f ? r : expm1f(r);
                u[j] = f2bf(r);
            }
            *reinterpret_cast<u16x8*>(&out[(size_t)d * HGAT_C + c]) = u;
        }
    }
}

// ---------------------------------------------------------------------------
// Pool stage A: 8 node-slices per graph -> partial sums.
// ---------------------------------------------------------------------------
__device__ __forceinline__ int lower_bound_batch(
    const int* __restrict__ batch, int N, int key)
{
    int lo = 0, hi = N;
    while (lo < hi) {
        const int mid = (lo + hi) >> 1;
        if (batch[mid] < key) lo = mid + 1; else hi = mid;
    }
    return lo;
}

__global__ __launch_bounds__(256) void pool_partial_kernel(
    const ushort_t* __restrict__ hfin, const int* __restrict__ batch,
    float* __restrict__ partial, int N)
{
    const int g   = blockIdx.x >> 3;
    const int s   = blockIdx.x & 7;
    const int t   = threadIdx.x;
    const int c   = t & 63;
    const int sub = t >> 6;

    const int beg = lower_bound_batch(batch, N, g);
    const int end = lower_bound_batch(batch, N, g + 1);
    const int len = end - beg;
    const int sl  = (len + 7) >> 3;
    const int sb  = beg + s * sl;
    const int se  = sb + sl < end ? sb + sl : end;

    float acc = 0.f;
    for (int n = sb + sub; n < se; n += 4)
        acc += bf2f(hfin[(size_t)n * HGAT_C + c]);

    __shared__ float sm[256];
    sm[t] = acc;
    __syncthreads();
    if (sub == 0)
        partial[(size_t)(g * 8 + s) * HGAT_C + c] =
            sm[c] + sm[64 + c] + sm[128 + c] + sm[192 + c];
}

// ---------------------------------------------------------------------------
// Pool stage B fused with final linear: one block per graph.
// ---------------------------------------------------------------------------
__global__ __launch_bounds__(64) void pool_final_fused_kernel(
    const float* __restrict__ partial, const int* __restrict__ batch,
    const float* __restrict__ Wa, const float* __restrict__ ba,
    float* __restrict__ out, int N)
{
    const int g = blockIdx.x;
    const int c = threadIdx.x;
    const int beg = lower_bound_batch(batch, N, g);
    const int end = lower_bound_batch(batch, N, g + 1);
    float s = 0.f;
#pragma unroll
    for (int k = 0; k < 8; ++k)
        s += partial[(size_t)(g * 8 + k) * HGAT_C + c];
    s /= fmaxf((float)(end - beg), 1.0f);

    __shared__ float pr[HGAT_C];
    pr[c] = s;
    __syncthreads();
    if (c < NACT) {
        float o = ba[c];
#pragma unroll
        for (int cc = 0; cc < HGAT_C; ++cc)
            o += pr[cc] * Wa[cc * NACT + c];
        out[g * NACT + c] = o;
    }
}

// ---------------------------------------------------------------------------
extern "C" void kernel_launch(void* const* d_in, const int* in_sizes, int n_in,
                              void* d_out, int out_size, void* d_ws, size_t ws_size,
                              hipStream_t stream)
{
    const float* x     = (const float*)d_in[0];
    const int*   ei    = (const int*)d_in[1];
    const int*   batch = (const int*)d_in[2];
    const float* W1    = (const float*)d_in[5];
    const float* as1   = (const float*)d_in[6];
    const float* ad1   = (const float*)d_in[7];
    const float* b1    = (const float*)d_in[8];
    const float* W2    = (const float*)d_in[9];
    const float* as2   = (const float*)d_in[10];
    const float* ad2   = (const float*)d_in[11];
    const float* b2    = (const float*)d_in[12];
    const float* Wa    = (const float*)d_in[13];
    const float* ba    = (const float*)d_in[14];

    const int N = in_sizes[0] / FIN;
    const int E = in_sizes[1] / 2;

    char* ws = (char*)d_ws;
    size_t off = 0;
    auto alloc = [&](size_t bytes) -> void* {
        void* p = ws + off;
        off += (bytes + 255) & ~(size_t)255;
        return p;
    };
    ushort_t* hb      = (ushort_t*)alloc((size_t)N * HGAT_HC * 2);
    ushort_t* hpost   = (ushort_t*)alloc((size_t)N * HGAT_HC * 2);
    ushort_t* Wt1     = (ushort_t*)alloc((size_t)FIN * HGAT_HC * 2);
    ushort_t* Wt2     = (ushort_t*)alloc((size_t)HGAT_HC * HGAT_HC * 2);
    ushort_t* attBt1  = (ushort_t*)alloc((size_t)16 * FIN * 2);
    ushort_t* attBt2  = (ushort_t*)alloc((size_t)16 * HGAT_HC * 2);
    float*    a_src   = (float*)alloc((size_t)N * 4 * 4);
    float*    a_dst   = (float*)alloc((size_t)N * 4 * 4);
    int*      rowptr  = (int*)alloc((size_t)(N + 1) * 4);
    int*      colsrc  = (int*)alloc((size_t)E * 4);
    int*      deg     = (int*)alloc((size_t)N * 4);
    int*      cursor  = (int*)alloc((size_t)N * 4);
    int*      bsum    = (int*)alloc(256 * 4);
    float*    partial = (float*)alloc((size_t)NGRAPHS * 8 * HGAT_C * 4);
    ushort_t* hfin    = hpost;
    (void)ws_size; (void)n_in; (void)out_size;

    const int gemmBlocks = (N + 63) / 64;
    const int aggBlocks  = (N + 7) / 8;     // 2 nodes/wave, 4 waves/block
    const int NB         = (N + 255) / 256;
    const int prepTot    = FIN * HGAT_HC + HGAT_HC * HGAT_HC + (FIN + HGAT_HC) * 8;

    // ---------------- CSR build + prep ----------------
    hipMemsetAsync(deg, 0, (size_t)N * 4, stream);
    count_prep_kernel<<<(E + prepTot + 255) / 256, 256, 0, stream>>>(
        ei, deg, W1, W2, as1, ad1, as2, ad2, Wt1, Wt2, attBt1, attBt2, E);
    block_sum_kernel<<<NB, 256, 0, stream>>>(deg, bsum, N);
    scan_bsums_kernel<<<1, 256, 0, stream>>>(bsum, NB);
    rowptr_kernel<<<NB, 256, 0, stream>>>(deg, bsum, rowptr, cursor, N);
    fill_csr_kernel<<<((E + 1) / 2 + 255) / 256, 256, 0, stream>>>(
        ei, cursor, colsrc, E);

    // ---------------- layer 1 ----------------
    gemm_mfma_att_kernel<FIN, true><<<gemmBlocks, 256, 0, stream>>>(
        x, Wt1, attBt1, hb, a_src, a_dst, N);
    aggregate_csr_kernel<0><<<aggBlocks, 256, 0, stream>>>(
        rowptr, colsrc, hb, a_src, a_dst, b1, hpost, N);

    // ---------------- layer 2 ----------------
    gemm_mfma_att_kernel<HGAT_HC, false><<<gemmBlocks, 256, 0, stream>>>(
        hpost, Wt2, attBt2, hb, a_src, a_dst, N);
    aggregate_csr_kernel<1><<<aggBlocks, 256, 0, stream>>>(
        rowptr, colsrc, hb, a_src, a_dst, b2, hfin, N);

    // ---------------- pool + final ----------------
    pool_partial_kernel<<<NGRAPHS * 8, 256, 0, stream>>>(hfin, batch, partial, N);
    pool_final_fused_kernel<<<NGRAPHS, 64, 0, stream>>>(
        partial, batch, Wa, ba, (float*)d_out, N);
}

// Round 16
// 238.880 us; speedup vs baseline: 2.1560x; 1.2947x over previous
//
#include <hip/hip_runtime.h>
#include <hip/hip_bf16.h>
#include <cstdint>
#include <cstddef>

#define FIN      128
#define HGAT_H   4
#define HGAT_C   64
#define HGAT_HC  256
#define NGRAPHS  64
#define NACT     32
#define LOG2E    1.4426950408889634f

typedef unsigned int   uint32;
typedef unsigned short ushort_t;

using short8 = __attribute__((ext_vector_type(8))) short;
using u16x8  = __attribute__((ext_vector_type(8))) ushort_t;
using f32x4  = __attribute__((ext_vector_type(4))) float;
using f32x2  = __attribute__((ext_vector_type(2))) float;

__device__ __forceinline__ float bf2f(ushort_t u) {
    return __uint_as_float(((uint32)u) << 16);
}
__device__ __forceinline__ float bflo(uint32 q) {
    return __uint_as_float(q << 16);
}
__device__ __forceinline__ float bfhi(uint32 q) {
    return __uint_as_float(q & 0xFFFF0000u);
}
__device__ __forceinline__ ushort_t f2bf(float f) {
    __hip_bfloat16 h = __float2bfloat16(f);   // RNE
    return *reinterpret_cast<ushort_t*>(&h);
}

// ---------------------------------------------------------------------------
// attB fold helper (hi/lo bf16 split, stored transposed [16][K]).
// ---------------------------------------------------------------------------
__device__ __forceinline__ void att_fold_one(
    const float* __restrict__ W, const float* __restrict__ as,
    const float* __restrict__ ad, ushort_t* __restrict__ attBt,
    int K, int idx)
{
    const int k = idx >> 3, j = idx & 7;
    const int h = j >> 1;
    const float* av = (j & 1) ? ad : as;
    float s = 0.f;
#pragma unroll 8
    for (int c = 0; c < HGAT_C; ++c)
        s += W[(size_t)k * HGAT_HC + h * 64 + c] * av[h * 64 + c];
    const ushort_t hi = f2bf(s);
    const float    lo = s - bf2f(hi);
    attBt[(size_t)j * K + k]       = hi;
    attBt[(size_t)(j + 8) * K + k] = f2bf(lo);
}

// ---------------------------------------------------------------------------
// Merged: per-bucket edge histogram (bucket = dst>>8) + weight/att prep.
// Blocks [0, CB): count a contiguous edge chunk via LDS histogram, then one
// global atomicAdd per bucket per block (few-k atomics total, not 850k).
// Blocks [CB, ...): prep elements.
// ---------------------------------------------------------------------------
#define CNT_BLOCKS 128

__global__ __launch_bounds__(256) void bucket_count_prep_kernel(
    const int* __restrict__ ei, int* __restrict__ bcnt,
    const float* __restrict__ W1, const float* __restrict__ W2,
    const float* __restrict__ as1, const float* __restrict__ ad1,
    const float* __restrict__ as2, const float* __restrict__ ad2,
    ushort_t* __restrict__ Wt1, ushort_t* __restrict__ Wt2,
    ushort_t* __restrict__ attBt1, ushort_t* __restrict__ attBt2, int E)
{
    const int t = threadIdx.x;
    if (blockIdx.x < CNT_BLOCKS) {
        __shared__ int hist[256];
        hist[t] = 0;
        __syncthreads();
        const int chunk = (E + CNT_BLOCKS - 1) / CNT_BLOCKS;
        const int lo = blockIdx.x * chunk;
        const int hi = min(lo + chunk, E);
        for (int e = lo + t; e < hi; e += 256)
            atomicAdd(&hist[ei[E + e] >> 8], 1);
        __syncthreads();
        if (hist[t] > 0) atomicAdd(&bcnt[t], hist[t]);
        return;
    }
    const int idx = (blockIdx.x - CNT_BLOCKS) * 256 + t;
    const int n1 = FIN * HGAT_HC;
    const int n2 = HGAT_HC * HGAT_HC;
    if (idx < n1) {
        const int k = idx >> 8, c = idx & 255;
        Wt1[(size_t)c * FIN + k] = f2bf(W1[idx]);
    } else if (idx < n1 + n2) {
        const int j = idx - n1;
        const int k = j >> 8, c = j & 255;
        Wt2[(size_t)c * HGAT_HC + k] = f2bf(W2[j]);
    } else if (idx < n1 + n2 + FIN * 8) {
        att_fold_one(W1, as1, ad1, attBt1, FIN, idx - n1 - n2);
    } else if (idx < n1 + n2 + (FIN + HGAT_HC) * 8) {
        att_fold_one(W2, as2, ad2, attBt2, HGAT_HC, idx - n1 - n2 - FIN * 8);
    }
}

// ---------------------------------------------------------------------------
// Exclusive scan of 256 bucket counts -> boff[0..256]; bcur init = boff.
// ---------------------------------------------------------------------------
__global__ __launch_bounds__(256) void bucket_scan_kernel(
    const int* __restrict__ bcnt, int* __restrict__ boff,
    int* __restrict__ bcur)
{
    __shared__ int sm[256];
    const int t = threadIdx.x;
    const int v = bcnt[t];
    sm[t] = v;
    __syncthreads();
#pragma unroll
    for (int off = 1; off < 256; off <<= 1) {
        const int u = (t >= off) ? sm[t - off] : 0;
        __syncthreads();
        sm[t] += u;
        __syncthreads();
    }
    const int ex = sm[t] - v;
    boff[t] = ex;
    bcur[t] = ex;
    if (t == 255) boff[256] = sm[255];
}

// ---------------------------------------------------------------------------
// Bucket scatter: each block takes a contiguous edge chunk, reserves space
// per bucket wholesale (LDS hist + one global atomicAdd per bucket), then
// writes (src,dst) int2 pairs into its contiguous per-bucket slices.
// ---------------------------------------------------------------------------
__global__ __launch_bounds__(256) void bucket_scatter_kernel(
    const int* __restrict__ ei, int* __restrict__ bcur,
    int2* __restrict__ staging, int E)
{
    __shared__ int hist[256];
    __shared__ int base[256];
    __shared__ int cur[256];
    const int t = threadIdx.x;
    hist[t] = 0;
    __syncthreads();

    const int chunk = 4096;
    const int lo = blockIdx.x * chunk;
    const int hi = min(lo + chunk, E);

    for (int e = lo + t; e < hi; e += 256)
        atomicAdd(&hist[ei[E + e] >> 8], 1);
    __syncthreads();
    if (hist[t] > 0) base[t] = atomicAdd(&bcur[t], hist[t]);
    cur[t] = 0;
    __syncthreads();

    for (int e = lo + t; e < hi; e += 256) {
        const int s = ei[e];
        const int d = ei[E + e];
        const int b = d >> 8;
        const int r = atomicAdd(&cur[b], 1);
        staging[base[b] + r] = make_int2(s, d);
    }
}

// ---------------------------------------------------------------------------
// Bucket fill: one block per bucket. LDS deg histogram -> LDS exclusive scan
// -> rowptr for the bucket's 256 nodes (global CSR offset = boff[b] + local)
// -> LDS-cursor scatter of src into the bucket's contiguous colsrc window
// (~13KB -> L2-local, no cross-XCD write amplification).
// ---------------------------------------------------------------------------
__global__ __launch_bounds__(256) void bucket_fill_kernel(
    const int2* __restrict__ staging, const int* __restrict__ boff,
    int* __restrict__ rowptr, int* __restrict__ colsrc, int N, int E)
{
    __shared__ int deg[256];
    __shared__ int ssc[256];
    __shared__ int cur[256];
    const int t  = threadIdx.x;
    const int b  = blockIdx.x;
    const int lo = boff[b];
    const int hi = boff[b + 1];

    deg[t] = 0;
    __syncthreads();
    for (int e = lo + t; e < hi; e += 256)
        atomicAdd(&deg[staging[e].y & 255], 1);
    __syncthreads();

    const int v = deg[t];
    ssc[t] = v;
    __syncthreads();
#pragma unroll
    for (int off = 1; off < 256; off <<= 1) {
        const int u = (t >= off) ? ssc[t - off] : 0;
        __syncthreads();
        ssc[t] += u;
        __syncthreads();
    }
    const int pre  = ssc[t] - v;         // local exclusive
    const int node = b * 256 + t;
    if (node < N) rowptr[node] = lo + pre;
    cur[t] = lo + pre;
    if (b == 0 && t == 0) rowptr[N] = E;
    __syncthreads();

    for (int e = lo + t; e < hi; e += 256) {
        const int2 sd = staging[e];
        const int pos = atomicAdd(&cur[sd.y & 255], 1);
        colsrc[pos] = sd.x;
    }
}

// ---------------------------------------------------------------------------
// MFMA GEMM + attention epilogue.  C[M,256] = A[M,K] @ Wt^T.
// (unchanged from r12/r14: A frags in registers, per-head LDS B panel with
// register prefetch, att dots via one extra MFMA on hi/lo attBt tile,
// C staged in LDS and copied out coalesced.)
// ---------------------------------------------------------------------------
template <int K, bool AF32>
__global__ __launch_bounds__(256) void gemm_mfma_att_kernel(
    const void* __restrict__ Av, const ushort_t* __restrict__ Bt,
    const ushort_t* __restrict__ attBt, ushort_t* __restrict__ Cb,
    float* __restrict__ a_src, float* __restrict__ a_dst, int M)
{
    constexpr int KK   = K / 32;
    constexpr int NPF  = K / 32;
    constexpr int BSTR = K + 8;
    constexpr int CSTR = 72;
    __shared__ ushort_t Bs[64 * BSTR];
    __shared__ ushort_t AttS[16 * BSTR];
    __shared__ ushort_t Cs[64 * CSTR];

    const int t  = threadIdx.x;
    const int w  = t >> 6;
    const int l  = t & 63;
    const int lg = l >> 4;
    const int lr = l & 15;
    const int rowbase = blockIdx.x * 64 + w * 16;

    const int srow  = t & 63;
    const int cbase = (t >> 6) * (K / 4);

    short8 af[KK];
    {
        const int arow = rowbase + lr;
        const int gr   = arow < M ? arow : M - 1;
        if (AF32) {
            const float* Ap = (const float*)Av + (size_t)gr * K;
#pragma unroll
            for (int kk = 0; kk < KK; ++kk) {
                const float4 v0 = *reinterpret_cast<const float4*>(Ap + kk * 32 + lg * 8);
                const float4 v1 = *reinterpret_cast<const float4*>(Ap + kk * 32 + lg * 8 + 4);
                short8 s;
                s[0] = (short)f2bf(v0.x); s[1] = (short)f2bf(v0.y);
                s[2] = (short)f2bf(v0.z); s[3] = (short)f2bf(v0.w);
                s[4] = (short)f2bf(v1.x); s[5] = (short)f2bf(v1.y);
                s[6] = (short)f2bf(v1.z); s[7] = (short)f2bf(v1.w);
                af[kk] = s;
            }
        } else {
            const ushort_t* Ap = (const ushort_t*)Av + (size_t)gr * K;
#pragma unroll
            for (int kk = 0; kk < KK; ++kk)
                af[kk] = *reinterpret_cast<const short8*>(Ap + kk * 32 + lg * 8);
        }
    }

    {
        const int r  = t & 15;
        const int cb = (t >> 4) * (K / 16);
        const ushort_t* src = attBt + (size_t)r * K + cb;
        ushort_t*       dst = &AttS[r * BSTR + cb];
#pragma unroll
        for (int j = 0; j < K / 128; ++j)
            *reinterpret_cast<u16x8*>(dst + j * 8) =
                *reinterpret_cast<const u16x8*>(src + j * 8);
    }
    {
        const ushort_t* src = Bt + (size_t)srow * K + cbase;
        ushort_t*       dst = &Bs[srow * BSTR + cbase];
#pragma unroll
        for (int j = 0; j < NPF; ++j)
            *reinterpret_cast<u16x8*>(dst + j * 8) =
                *reinterpret_cast<const u16x8*>(src + j * 8);
    }
    __syncthreads();

    {
        f32x4 aacc = {0.f, 0.f, 0.f, 0.f};
#pragma unroll
        for (int kk = 0; kk < KK; ++kk) {
            const short8 bfr = *reinterpret_cast<const short8*>(
                &AttS[lr * BSTR + kk * 32 + lg * 8]);
            aacc = __builtin_amdgcn_mfma_f32_16x16x32_bf16(af[kk], bfr, aacc, 0, 0, 0);
        }
#pragma unroll
        for (int reg = 0; reg < 4; ++reg) {
            const int gm = rowbase + lg * 4 + reg;
            const float v = aacc[reg] + __shfl_xor(aacc[reg], 8);   // hi + lo
            if (lr < 8 && gm < M) {
                const int hh = lr >> 1;
                if (lr & 1) a_dst[gm * 4 + hh] = v * LOG2E;
                else        a_src[gm * 4 + hh] = v * LOG2E;
            }
        }
    }

    u16x8 pf[NPF];
#pragma unroll
    for (int head = 0; head < HGAT_H; ++head) {
        if (head < HGAT_H - 1) {
            const ushort_t* src =
                Bt + ((size_t)(head + 1) * 64 + srow) * K + cbase;
#pragma unroll
            for (int j = 0; j < NPF; ++j)
                pf[j] = *reinterpret_cast<const u16x8*>(src + j * 8);
        }

        f32x4 acc[4];
#pragma unroll
        for (int ct = 0; ct < 4; ++ct) acc[ct] = {0.f, 0.f, 0.f, 0.f};

#pragma unroll
        for (int kk = 0; kk < KK; ++kk) {
            short8 bfr[4];
#pragma unroll
            for (int ct = 0; ct < 4; ++ct)
                bfr[ct] = *reinterpret_cast<const short8*>(
                    &Bs[(ct * 16 + lr) * BSTR + kk * 32 + lg * 8]);
#pragma unroll
            for (int ct = 0; ct < 4; ++ct)
                acc[ct] = __builtin_amdgcn_mfma_f32_16x16x32_bf16(
                    af[kk], bfr[ct], acc[ct], 0, 0, 0);
        }

#pragma unroll
        for (int reg = 0; reg < 4; ++reg) {
            const int r = w * 16 + lg * 4 + reg;
#pragma unroll
            for (int ct = 0; ct < 4; ++ct)
                Cs[r * CSTR + ct * 16 + lr] = f2bf(acc[ct][reg]);
        }
        __syncthreads();

        const int n0 = head * 64;
        {
            const int cc = (t & 7) * 8;
#pragma unroll
            for (int it = 0; it < 2; ++it) {
                const int r  = (t >> 3) + it * 32;
                const int gm = blockIdx.x * 64 + r;
                if (gm < M) {
                    const u16x8 val = *reinterpret_cast<const u16x8*>(&Cs[r * CSTR + cc]);
                    *reinterpret_cast<u16x8*>(&Cb[(size_t)gm * HGAT_HC + n0 + cc]) = val;
                }
            }
        }

        if (head < HGAT_H - 1) {
            ushort_t* dst = &Bs[srow * BSTR + cbase];
#pragma unroll
            for (int j = 0; j < NPF; ++j)
                *reinterpret_cast<u16x8*>(dst + j * 8) = pf[j];
        }
        __syncthreads();
    }
}

// ---------------------------------------------------------------------------
// CSR aggregate, TWO nodes per wave, uint4 gather (unchanged from r14).
// ---------------------------------------------------------------------------
template <int MODE>
__global__ __launch_bounds__(256) void aggregate_csr_kernel(
    const int* __restrict__ rowptr, const int* __restrict__ colsrc,
    const ushort_t* __restrict__ hb, const float* __restrict__ a_src,
    const float* __restrict__ a_dst, const float* __restrict__ bias,
    ushort_t* __restrict__ out, int N)
{
    const int wave = (blockIdx.x * 256 + threadIdx.x) >> 6;
    const int lane = threadIdx.x & 63;
    const int half = lane >> 5;
    const int hl   = lane & 31;
    const int d    = wave * 2 + half;
    if (d >= N) return;

    const int c0 = hl * 8;
    const int h  = hl >> 3;
    const float ad = a_dst[d * 4 + h];

    f32x2 a01 = {0.f, 0.f}, a23 = {0.f, 0.f}, a45 = {0.f, 0.f}, a67 = {0.f, 0.f};
    float den = 0.f;

    const int beg = rowptr[d], end = rowptr[d + 1];
    int i = beg;
    for (; i + 4 <= end; i += 4) {
        int   sv[4];
        float av[4];
        uint4 qv[4];
#pragma unroll
        for (int j = 0; j < 4; ++j) sv[j] = colsrc[i + j];
#pragma unroll
        for (int j = 0; j < 4; ++j) av[j] = a_src[sv[j] * 4 + h];
#pragma unroll
        for (int j = 0; j < 4; ++j)
            qv[j] = *reinterpret_cast<const uint4*>(&hb[(size_t)sv[j] * HGAT_HC + c0]);
#pragma unroll
        for (int j = 0; j < 4; ++j) {
            float ee = av[j] + ad;
            ee = fmaxf(ee, 0.2f * ee);
            const float wgt = __builtin_amdgcn_exp2f(ee);
            const f32x2 w2 = {wgt, wgt};
            a01 += w2 * f32x2{bflo(qv[j].x), bfhi(qv[j].x)};
            a23 += w2 * f32x2{bflo(qv[j].y), bfhi(qv[j].y)};
            a45 += w2 * f32x2{bflo(qv[j].z), bfhi(qv[j].z)};
            a67 += w2 * f32x2{bflo(qv[j].w), bfhi(qv[j].w)};
            den += wgt;
        }
    }
    for (; i < end; ++i) {
        const int s = colsrc[i];
        float ee = a_src[s * 4 + h] + ad;
        ee = fmaxf(ee, 0.2f * ee);
        const float wgt = __builtin_amdgcn_exp2f(ee);
        const uint4 q = *reinterpret_cast<const uint4*>(&hb[(size_t)s * HGAT_HC + c0]);
        const f32x2 w2 = {wgt, wgt};
        a01 += w2 * f32x2{bflo(q.x), bfhi(q.x)};
        a23 += w2 * f32x2{bflo(q.y), bfhi(q.y)};
        a45 += w2 * f32x2{bflo(q.z), bfhi(q.z)};
        a67 += w2 * f32x2{bflo(q.w), bfhi(q.w)};
        den += wgt;
    }
    {   // self loop
        float ee = a_src[d * 4 + h] + ad;
        ee = fmaxf(ee, 0.2f * ee);
        const float wgt = __builtin_amdgcn_exp2f(ee);
        const uint4 q = *reinterpret_cast<const uint4*>(&hb[(size_t)d * HGAT_HC + c0]);
        const f32x2 w2 = {wgt, wgt};
        a01 += w2 * f32x2{bflo(q.x), bfhi(q.x)};
        a23 += w2 * f32x2{bflo(q.y), bfhi(q.y)};
        a45 += w2 * f32x2{bflo(q.z), bfhi(q.z)};
        a67 += w2 * f32x2{bflo(q.w), bfhi(q.w)};
        den += wgt;
    }

    const float inv = 1.0f / den;
    float v[8] = {a01.x * inv, a01.y * inv, a23.x * inv, a23.y * inv,
                  a45.x * inv, a45.y * inv, a67.x * inv, a67.y * inv};

    if (MODE == 0) {
        const float4 b0 = *reinterpret_cast<const float4*>(&bias[c0]);
        const float4 b1 = *reinterpret_cast<const float4*>(&bias[c0 + 4]);
        v[0] += b0.x; v[1] += b0.y; v[2] += b0.z; v[3] += b0.w;
        v[4] += b1.x; v[5] += b1.y; v[6] += b1.z; v[7] += b1.w;
        u16x8 u;
#pragma unroll
        for (int j = 0; j < 8; ++j) {
            const float r = v[j] > 0.f ? v[j] : expm1f(v[j]);
            u[j] = f2bf(r);
        }
        *reinterpret_cast<u16x8*>(&out[(size_t)d * HGAT_HC + c0]) = u;
    } else {
#pragma unroll
        for (int j = 0; j < 8; ++j) {
            v[j] += __shfl_xor(v[j], 8);
            v[j] += __shfl_xor(v[j], 16);
        }
        if (hl < 8) {
            const int c = hl * 8;
            const float4 b0 = *reinterpret_cast<const float4*>(&bias[c]);
            const float4 b1 = *reinterpret_cast<const float4*>(&bias[c + 4]);
            const float bb[8] = {b0.x, b0.y, b0.z, b0.w, b1.x, b1.y, b1.z, b1.w};
            u16x8 u;
#pragma unroll
            for (int j = 0; j < 8; ++j) {
                float r = 0.25f * v[j] + bb[j];
                r = r > 0.f ? r : expm1f(r);
                u[j] = f2bf(r);
            }
            *reinterpret_cast<u16x8*>(&out[(size_t)d * HGAT_C + c]) = u;
        }
    }
}

// ---------------------------------------------------------------------------
// Pool stage A + fused stage B (unchanged).
// ---------------------------------------------------------------------------
__device__ __forceinline__ int lower_bound_batch(
    const int* __restrict__ batch, int N, int key)
{
    int lo = 0, hi = N;
    while (lo < hi) {
        const int mid = (lo + hi) >> 1;
        if (batch[mid] < key) lo = mid + 1; else hi = mid;
    }
    return lo;
}

__global__ __launch_bounds__(256) void pool_partial_kernel(
    const ushort_t* __restrict__ hfin, const int* __restrict__ batch,
    float* __restrict__ partial, int N)
{
    const int g   = blockIdx.x >> 3;
    const int s   = blockIdx.x & 7;
    const int t   = threadIdx.x;
    const int c   = t & 63;
    const int sub = t >> 6;

    const int beg = lower_bound_batch(batch, N, g);
    const int end = lower_bound_batch(batch, N, g + 1);
    const int len = end - beg;
    const int sl  = (len + 7) >> 3;
    const int sb  = beg + s * sl;
    const int se  = sb + sl < end ? sb + sl : end;

    float acc = 0.f;
    for (int n = sb + sub; n < se; n += 4)
        acc += bf2f(hfin[(size_t)n * HGAT_C + c]);

    __shared__ float sm[256];
    sm[t] = acc;
    __syncthreads();
    if (sub == 0)
        partial[(size_t)(g * 8 + s) * HGAT_C + c] =
            sm[c] + sm[64 + c] + sm[128 + c] + sm[192 + c];
}

__global__ __launch_bounds__(64) void pool_final_fused_kernel(
    const float* __restrict__ partial, const int* __restrict__ batch,
    const float* __restrict__ Wa, const float* __restrict__ ba,
    float* __restrict__ out, int N)
{
    const int g = blockIdx.x;
    const int c = threadIdx.x;
    const int beg = lower_bound_batch(batch, N, g);
    const int end = lower_bound_batch(batch, N, g + 1);
    float s = 0.f;
#pragma unroll
    for (int k = 0; k < 8; ++k)
        s += partial[(size_t)(g * 8 + k) * HGAT_C + c];
    s /= fmaxf((float)(end - beg), 1.0f);

    __shared__ float pr[HGAT_C];
    pr[c] = s;
    __syncthreads();
    if (c < NACT) {
        float o = ba[c];
#pragma unroll
        for (int cc = 0; cc < HGAT_C; ++cc)
            o += pr[cc] * Wa[cc * NACT + c];
        out[g * NACT + c] = o;
    }
}

// ---------------------------------------------------------------------------
extern "C" void kernel_launch(void* const* d_in, const int* in_sizes, int n_in,
                              void* d_out, int out_size, void* d_ws, size_t ws_size,
                              hipStream_t stream)
{
    const float* x     = (const float*)d_in[0];
    const int*   ei    = (const int*)d_in[1];
    const int*   batch = (const int*)d_in[2];
    const float* W1    = (const float*)d_in[5];
    const float* as1   = (const float*)d_in[6];
    const float* ad1   = (const float*)d_in[7];
    const float* b1    = (const float*)d_in[8];
    const float* W2    = (const float*)d_in[9];
    const float* as2   = (const float*)d_in[10];
    const float* ad2   = (const float*)d_in[11];
    const float* b2    = (const float*)d_in[12];
    const float* Wa    = (const float*)d_in[13];
    const float* ba    = (const float*)d_in[14];

    const int N = in_sizes[0] / FIN;
    const int E = in_sizes[1] / 2;

    char* ws = (char*)d_ws;
    size_t off = 0;
    auto alloc = [&](size_t bytes) -> void* {
        void* p = ws + off;
        off += (bytes + 255) & ~(size_t)255;
        return p;
    };
    ushort_t* hb      = (ushort_t*)alloc((size_t)N * HGAT_HC * 2);
    ushort_t* hpost   = (ushort_t*)alloc((size_t)N * HGAT_HC * 2);
    ushort_t* Wt1     = (ushort_t*)alloc((size_t)FIN * HGAT_HC * 2);
    ushort_t* Wt2     = (ushort_t*)alloc((size_t)HGAT_HC * HGAT_HC * 2);
    ushort_t* attBt1  = (ushort_t*)alloc((size_t)16 * FIN * 2);
    ushort_t* attBt2  = (ushort_t*)alloc((size_t)16 * HGAT_HC * 2);
    float*    a_src   = (float*)alloc((size_t)N * 4 * 4);
    float*    a_dst   = (float*)alloc((size_t)N * 4 * 4);
    int*      rowptr  = (int*)alloc((size_t)(N + 1) * 4);
    int*      colsrc  = (int*)alloc((size_t)E * 4);
    int2*     staging = (int2*)alloc((size_t)E * 8);
    int*      bcnt    = (int*)alloc(256 * 4);
    int*      boff    = (int*)alloc(257 * 4);
    int*      bcur    = (int*)alloc(256 * 4);
    float*    partial = (float*)alloc((size_t)NGRAPHS * 8 * HGAT_C * 4);
    ushort_t* hfin    = hpost;
    (void)ws_size; (void)n_in; (void)out_size;

    const int gemmBlocks = (N + 63) / 64;
    const int aggBlocks  = (N + 7) / 8;
    const int NBKT       = (N + 255) >> 8;             // buckets (<=256)
    const int prepTot    = FIN * HGAT_HC + HGAT_HC * HGAT_HC + (FIN + HGAT_HC) * 8;
    const int prepBlocks = (prepTot + 255) / 256;

    // ---------------- CSR build: bucketed counting sort ----------------
    hipMemsetAsync(bcnt, 0, 256 * 4, stream);
    bucket_count_prep_kernel<<<CNT_BLOCKS + prepBlocks, 256, 0, stream>>>(
        ei, bcnt, W1, W2, as1, ad1, as2, ad2, Wt1, Wt2, attBt1, attBt2, E);
    bucket_scan_kernel<<<1, 256, 0, stream>>>(bcnt, boff, bcur);
    bucket_scatter_kernel<<<(E + 4095) / 4096, 256, 0, stream>>>(
        ei, bcur, staging, E);
    bucket_fill_kernel<<<NBKT, 256, 0, stream>>>(
        staging, boff, rowptr, colsrc, N, E);

    // ---------------- layer 1 ----------------
    gemm_mfma_att_kernel<FIN, true><<<gemmBlocks, 256, 0, stream>>>(
        x, Wt1, attBt1, hb, a_src, a_dst, N);
    aggregate_csr_kernel<0><<<aggBlocks, 256, 0, stream>>>(
        rowptr, colsrc, hb, a_src, a_dst, b1, hpost, N);

    // ---------------- layer 2 ----------------
    gemm_mfma_att_kernel<HGAT_HC, false><<<gemmBlocks, 256, 0, stream>>>(
        hpost, Wt2, attBt2, hb, a_src, a_dst, N);
    aggregate_csr_kernel<1><<<aggBlocks, 256, 0, stream>>>(
        rowptr, colsrc, hb, a_src, a_dst, b2, hfin, N);

    // ---------------- pool + final ----------------
    pool_partial_kernel<<<NGRAPHS * 8, 256, 0, stream>>>(hfin, batch, partial, N);
    pool_final_fused_kernel<<<NGRAPHS, 64, 0, stream>>>(
        partial, batch, Wa, ba, (float*)d_out, N);
}

// Round 17
// 225.607 us; speedup vs baseline: 2.2828x; 1.0588x over previous
//
#include <hip/hip_runtime.h>
#include <hip/hip_bf16.h>
#include <cstdint>
#include <cstddef>

#define FIN      128
#define HGAT_H   4
#define HGAT_C   64
#define HGAT_HC  256
#define NGRAPHS  64
#define NACT     32
#define LOG2E    1.4426950408889634f
#define CNT_BLOCKS 128

typedef unsigned int   uint32;
typedef unsigned short ushort_t;

using short8 = __attribute__((ext_vector_type(8))) short;
using u16x8  = __attribute__((ext_vector_type(8))) ushort_t;
using f32x4  = __attribute__((ext_vector_type(4))) float;
using f32x2  = __attribute__((ext_vector_type(2))) float;

__device__ __forceinline__ float bf2f(ushort_t u) {
    return __uint_as_float(((uint32)u) << 16);
}
__device__ __forceinline__ float bflo(uint32 q) {
    return __uint_as_float(q << 16);
}
__device__ __forceinline__ float bfhi(uint32 q) {
    return __uint_as_float(q & 0xFFFF0000u);
}
__device__ __forceinline__ ushort_t f2bf(float f) {
    __hip_bfloat16 h = __float2bfloat16(f);   // RNE
    return *reinterpret_cast<ushort_t*>(&h);
}

// ---------------------------------------------------------------------------
// attB fold helper (hi/lo bf16 split, stored transposed [16][K]).
// ---------------------------------------------------------------------------
__device__ __forceinline__ void att_fold_one(
    const float* __restrict__ W, const float* __restrict__ as,
    const float* __restrict__ ad, ushort_t* __restrict__ attBt,
    int K, int idx)
{
    const int k = idx >> 3, j = idx & 7;
    const int h = j >> 1;
    const float* av = (j & 1) ? ad : as;
    float s = 0.f;
#pragma unroll 8
    for (int c = 0; c < HGAT_C; ++c)
        s += W[(size_t)k * HGAT_HC + h * 64 + c] * av[h * 64 + c];
    const ushort_t hi = f2bf(s);
    const float    lo = s - bf2f(hi);
    attBt[(size_t)j * K + k]       = hi;
    attBt[(size_t)(j + 8) * K + k] = f2bf(lo);
}

// ---------------------------------------------------------------------------
// Merged: per-bucket edge histogram (bucket = dst>>8, PER-BLOCK hist arrays,
// no global atomics, no memset) + weight/att prep.
// ---------------------------------------------------------------------------
__global__ __launch_bounds__(256) void bucket_count_prep_kernel(
    const int* __restrict__ ei, int* __restrict__ bhist,
    const float* __restrict__ W1, const float* __restrict__ W2,
    const float* __restrict__ as1, const float* __restrict__ ad1,
    const float* __restrict__ as2, const float* __restrict__ ad2,
    ushort_t* __restrict__ Wt1, ushort_t* __restrict__ Wt2,
    ushort_t* __restrict__ attBt1, ushort_t* __restrict__ attBt2, int E)
{
    const int t = threadIdx.x;
    if (blockIdx.x < CNT_BLOCKS) {
        __shared__ int hist[256];
        hist[t] = 0;
        __syncthreads();
        const int chunk = (E + CNT_BLOCKS - 1) / CNT_BLOCKS;
        const int lo = blockIdx.x * chunk;
        const int hi = min(lo + chunk, E);
        for (int e = lo + t; e < hi; e += 256)
            atomicAdd(&hist[ei[E + e] >> 8], 1);
        __syncthreads();
        bhist[blockIdx.x * 256 + t] = hist[t];
        return;
    }
    const int idx = (blockIdx.x - CNT_BLOCKS) * 256 + t;
    const int n1 = FIN * HGAT_HC;
    const int n2 = HGAT_HC * HGAT_HC;
    if (idx < n1) {
        const int k = idx >> 8, c = idx & 255;
        Wt1[(size_t)c * FIN + k] = f2bf(W1[idx]);
    } else if (idx < n1 + n2) {
        const int j = idx - n1;
        const int k = j >> 8, c = j & 255;
        Wt2[(size_t)c * HGAT_HC + k] = f2bf(W2[j]);
    } else if (idx < n1 + n2 + FIN * 8) {
        att_fold_one(W1, as1, ad1, attBt1, FIN, idx - n1 - n2);
    } else if (idx < n1 + n2 + (FIN + HGAT_HC) * 8) {
        att_fold_one(W2, as2, ad2, attBt2, HGAT_HC, idx - n1 - n2 - FIN * 8);
    }
}

// ---------------------------------------------------------------------------
// Sum per-block hists + exclusive scan -> boff[0..256]; bcur init = boff.
// ---------------------------------------------------------------------------
__global__ __launch_bounds__(256) void bucket_scan_kernel(
    const int* __restrict__ bhist, int* __restrict__ boff,
    int* __restrict__ bcur)
{
    __shared__ int sm[256];
    const int t = threadIdx.x;
    int v = 0;
    for (int j = 0; j < CNT_BLOCKS; ++j) v += bhist[j * 256 + t];
    sm[t] = v;
    __syncthreads();
#pragma unroll
    for (int off = 1; off < 256; off <<= 1) {
        const int u = (t >= off) ? sm[t - off] : 0;
        __syncthreads();
        sm[t] += u;
        __syncthreads();
    }
    const int ex = sm[t] - v;
    boff[t] = ex;
    bcur[t] = ex;
    if (t == 255) boff[256] = sm[255];
}

// ---------------------------------------------------------------------------
// Scatter body: block takes a contiguous edge chunk, reserves per-bucket
// space wholesale, writes (src,dst) pairs into contiguous slices.
// ---------------------------------------------------------------------------
__device__ __forceinline__ void scatter_body(
    const int* __restrict__ ei, int* __restrict__ bcur,
    int2* __restrict__ staging, int E, int blk)
{
    __shared__ int hist[256];
    __shared__ int base[256];
    __shared__ int cur[256];
    const int t = threadIdx.x;
    hist[t] = 0;
    __syncthreads();

    const int chunk = 4096;
    const int lo = blk * chunk;
    const int hi = min(lo + chunk, E);

    for (int e = lo + t; e < hi; e += 256)
        atomicAdd(&hist[ei[E + e] >> 8], 1);
    __syncthreads();
    if (hist[t] > 0) base[t] = atomicAdd(&bcur[t], hist[t]);
    cur[t] = 0;
    __syncthreads();

    for (int e = lo + t; e < hi; e += 256) {
        const int s = ei[e];
        const int d = ei[E + e];
        const int b = d >> 8;
        const int r = atomicAdd(&cur[b], 1);
        staging[base[b] + r] = make_int2(s, d);
    }
}

// ---------------------------------------------------------------------------
// Bucket fill: one block per bucket (unchanged from r16).
// ---------------------------------------------------------------------------
__global__ __launch_bounds__(256) void bucket_fill_kernel(
    const int2* __restrict__ staging, const int* __restrict__ boff,
    int* __restrict__ rowptr, int* __restrict__ colsrc, int N, int E)
{
    __shared__ int deg[256];
    __shared__ int ssc[256];
    __shared__ int cur[256];
    const int t  = threadIdx.x;
    const int b  = blockIdx.x;
    const int lo = boff[b];
    const int hi = boff[b + 1];

    deg[t] = 0;
    __syncthreads();
    for (int e = lo + t; e < hi; e += 256)
        atomicAdd(&deg[staging[e].y & 255], 1);
    __syncthreads();

    const int v = deg[t];
    ssc[t] = v;
    __syncthreads();
#pragma unroll
    for (int off = 1; off < 256; off <<= 1) {
        const int u = (t >= off) ? ssc[t - off] : 0;
        __syncthreads();
        ssc[t] += u;
        __syncthreads();
    }
    const int pre  = ssc[t] - v;
    const int node = b * 256 + t;
    if (node < N) rowptr[node] = lo + pre;
    cur[t] = lo + pre;
    if (b == 0 && t == 0) rowptr[N] = E;
    __syncthreads();

    for (int e = lo + t; e < hi; e += 256) {
        const int2 sd = staging[e];
        const int pos = atomicAdd(&cur[sd.y & 255], 1);
        colsrc[pos] = sd.x;
    }
}

// ---------------------------------------------------------------------------
// GEMM body (device fn).  C[M,256] = A[M,K] @ Wt^T.  Same structure as r12.
// ---------------------------------------------------------------------------
template <int K, bool AF32>
__device__ __forceinline__ void gemm_body(
    const void* __restrict__ Av, const ushort_t* __restrict__ Bt,
    const ushort_t* __restrict__ attBt, ushort_t* __restrict__ Cb,
    float* __restrict__ a_src, float* __restrict__ a_dst, int M, int blk)
{
    constexpr int KK   = K / 32;
    constexpr int NPF  = K / 32;
    constexpr int BSTR = K + 8;
    constexpr int CSTR = 72;
    __shared__ ushort_t Bs[64 * BSTR];
    __shared__ ushort_t AttS[16 * BSTR];
    __shared__ ushort_t Cs[64 * CSTR];

    const int t  = threadIdx.x;
    const int w  = t >> 6;
    const int l  = t & 63;
    const int lg = l >> 4;
    const int lr = l & 15;
    const int rowbase = blk * 64 + w * 16;

    const int srow  = t & 63;
    const int cbase = (t >> 6) * (K / 4);

    short8 af[KK];
    {
        const int arow = rowbase + lr;
        const int gr   = arow < M ? arow : M - 1;
        if (AF32) {
            const float* Ap = (const float*)Av + (size_t)gr * K;
#pragma unroll
            for (int kk = 0; kk < KK; ++kk) {
                const float4 v0 = *reinterpret_cast<const float4*>(Ap + kk * 32 + lg * 8);
                const float4 v1 = *reinterpret_cast<const float4*>(Ap + kk * 32 + lg * 8 + 4);
                short8 s;
                s[0] = (short)f2bf(v0.x); s[1] = (short)f2bf(v0.y);
                s[2] = (short)f2bf(v0.z); s[3] = (short)f2bf(v0.w);
                s[4] = (short)f2bf(v1.x); s[5] = (short)f2bf(v1.y);
                s[6] = (short)f2bf(v1.z); s[7] = (short)f2bf(v1.w);
                af[kk] = s;
            }
        } else {
            const ushort_t* Ap = (const ushort_t*)Av + (size_t)gr * K;
#pragma unroll
            for (int kk = 0; kk < KK; ++kk)
                af[kk] = *reinterpret_cast<const short8*>(Ap + kk * 32 + lg * 8);
        }
    }

    {
        const int r  = t & 15;
        const int cb = (t >> 4) * (K / 16);
        const ushort_t* src = attBt + (size_t)r * K + cb;
        ushort_t*       dst = &AttS[r * BSTR + cb];
#pragma unroll
        for (int j = 0; j < K / 128; ++j)
            *reinterpret_cast<u16x8*>(dst + j * 8) =
                *reinterpret_cast<const u16x8*>(src + j * 8);
    }
    {
        const ushort_t* src = Bt + (size_t)srow * K + cbase;
        ushort_t*       dst = &Bs[srow * BSTR + cbase];
#pragma unroll
        for (int j = 0; j < NPF; ++j)
            *reinterpret_cast<u16x8*>(dst + j * 8) =
                *reinterpret_cast<const u16x8*>(src + j * 8);
    }
    __syncthreads();

    {
        f32x4 aacc = {0.f, 0.f, 0.f, 0.f};
#pragma unroll
        for (int kk = 0; kk < KK; ++kk) {
            const short8 bfr = *reinterpret_cast<const short8*>(
                &AttS[lr * BSTR + kk * 32 + lg * 8]);
            aacc = __builtin_amdgcn_mfma_f32_16x16x32_bf16(af[kk], bfr, aacc, 0, 0, 0);
        }
#pragma unroll
        for (int reg = 0; reg < 4; ++reg) {
            const int gm = rowbase + lg * 4 + reg;
            const float v = aacc[reg] + __shfl_xor(aacc[reg], 8);   // hi + lo
            if (lr < 8 && gm < M) {
                const int hh = lr >> 1;
                if (lr & 1) a_dst[gm * 4 + hh] = v * LOG2E;
                else        a_src[gm * 4 + hh] = v * LOG2E;
            }
        }
    }

    u16x8 pf[NPF];
#pragma unroll
    for (int head = 0; head < HGAT_H; ++head) {
        if (head < HGAT_H - 1) {
            const ushort_t* src =
                Bt + ((size_t)(head + 1) * 64 + srow) * K + cbase;
#pragma unroll
            for (int j = 0; j < NPF; ++j)
                pf[j] = *reinterpret_cast<const u16x8*>(src + j * 8);
        }

        f32x4 acc[4];
#pragma unroll
        for (int ct = 0; ct < 4; ++ct) acc[ct] = {0.f, 0.f, 0.f, 0.f};

#pragma unroll
        for (int kk = 0; kk < KK; ++kk) {
            short8 bfr[4];
#pragma unroll
            for (int ct = 0; ct < 4; ++ct)
                bfr[ct] = *reinterpret_cast<const short8*>(
                    &Bs[(ct * 16 + lr) * BSTR + kk * 32 + lg * 8]);
#pragma unroll
            for (int ct = 0; ct < 4; ++ct)
                acc[ct] = __builtin_amdgcn_mfma_f32_16x16x32_bf16(
                    af[kk], bfr[ct], acc[ct], 0, 0, 0);
        }

#pragma unroll
        for (int reg = 0; reg < 4; ++reg) {
            const int r = w * 16 + lg * 4 + reg;
#pragma unroll
            for (int ct = 0; ct < 4; ++ct)
                Cs[r * CSTR + ct * 16 + lr] = f2bf(acc[ct][reg]);
        }
        __syncthreads();

        const int n0 = head * 64;
        {
            const int cc = (t & 7) * 8;
#pragma unroll
            for (int it = 0; it < 2; ++it) {
                const int r  = (t >> 3) + it * 32;
                const int gm = blk * 64 + r;
                if (gm < M) {
                    const u16x8 val = *reinterpret_cast<const u16x8*>(&Cs[r * CSTR + cc]);
                    *reinterpret_cast<u16x8*>(&Cb[(size_t)gm * HGAT_HC + n0 + cc]) = val;
                }
            }
        }

        if (head < HGAT_H - 1) {
            ushort_t* dst = &Bs[srow * BSTR + cbase];
#pragma unroll
            for (int j = 0; j < NPF; ++j)
                *reinterpret_cast<u16x8*>(dst + j * 8) = pf[j];
        }
        __syncthreads();
    }
}

// ---------------------------------------------------------------------------
// Merged dispatch: blocks [0,SB) scatter edges; blocks [SB,..) run GEMM1.
// (scatter and GEMM1 are independent; grid-split = in-launch concurrency.)
// ---------------------------------------------------------------------------
__global__ __launch_bounds__(256) void scatter_gemm1_kernel(
    const int* __restrict__ ei, int* __restrict__ bcur,
    int2* __restrict__ staging, int E, int SB,
    const float* __restrict__ x, const ushort_t* __restrict__ Wt1,
    const ushort_t* __restrict__ attBt1, ushort_t* __restrict__ hb,
    float* __restrict__ a_src, float* __restrict__ a_dst, int M)
{
    if ((int)blockIdx.x < SB) {
        scatter_body(ei, bcur, staging, E, blockIdx.x);
        return;
    }
    gemm_body<FIN, true>(x, Wt1, attBt1, hb, a_src, a_dst, M,
                         blockIdx.x - SB);
}

__global__ __launch_bounds__(256) void gemm2_kernel(
    const ushort_t* __restrict__ A, const ushort_t* __restrict__ Wt2,
    const ushort_t* __restrict__ attBt2, ushort_t* __restrict__ hb,
    float* __restrict__ a_src, float* __restrict__ a_dst, int M)
{
    gemm_body<HGAT_HC, false>(A, Wt2, attBt2, hb, a_src, a_dst, M, blockIdx.x);
}

// ---------------------------------------------------------------------------
// CSR aggregate, TWO nodes per wave, uint4 gather (unchanged from r14).
// ---------------------------------------------------------------------------
template <int MODE>
__global__ __launch_bounds__(256) void aggregate_csr_kernel(
    const int* __restrict__ rowptr, const int* __restrict__ colsrc,
    const ushort_t* __restrict__ hb, const float* __restrict__ a_src,
    const float* __restrict__ a_dst, const float* __restrict__ bias,
    ushort_t* __restrict__ out, int N)
{
    const int wave = (blockIdx.x * 256 + threadIdx.x) >> 6;
    const int lane = threadIdx.x & 63;
    const int half = lane >> 5;
    const int hl   = lane & 31;
    const int d    = wave * 2 + half;
    if (d >= N) return;

    const int c0 = hl * 8;
    const int h  = hl >> 3;
    const float ad = a_dst[d * 4 + h];

    f32x2 a01 = {0.f, 0.f}, a23 = {0.f, 0.f}, a45 = {0.f, 0.f}, a67 = {0.f, 0.f};
    float den = 0.f;

    const int beg = rowptr[d], end = rowptr[d + 1];
    int i = beg;
    for (; i + 4 <= end; i += 4) {
        int   sv[4];
        float av[4];
        uint4 qv[4];
#pragma unroll
        for (int j = 0; j < 4; ++j) sv[j] = colsrc[i + j];
#pragma unroll
        for (int j = 0; j < 4; ++j) av[j] = a_src[sv[j] * 4 + h];
#pragma unroll
        for (int j = 0; j < 4; ++j)
            qv[j] = *reinterpret_cast<const uint4*>(&hb[(size_t)sv[j] * HGAT_HC + c0]);
#pragma unroll
        for (int j = 0; j < 4; ++j) {
            float ee = av[j] + ad;
            ee = fmaxf(ee, 0.2f * ee);
            const float wgt = __builtin_amdgcn_exp2f(ee);
            const f32x2 w2 = {wgt, wgt};
            a01 += w2 * f32x2{bflo(qv[j].x), bfhi(qv[j].x)};
            a23 += w2 * f32x2{bflo(qv[j].y), bfhi(qv[j].y)};
            a45 += w2 * f32x2{bflo(qv[j].z), bfhi(qv[j].z)};
            a67 += w2 * f32x2{bflo(qv[j].w), bfhi(qv[j].w)};
            den += wgt;
        }
    }
    for (; i < end; ++i) {
        const int s = colsrc[i];
        float ee = a_src[s * 4 + h] + ad;
        ee = fmaxf(ee, 0.2f * ee);
        const float wgt = __builtin_amdgcn_exp2f(ee);
        const uint4 q = *reinterpret_cast<const uint4*>(&hb[(size_t)s * HGAT_HC + c0]);
        const f32x2 w2 = {wgt, wgt};
        a01 += w2 * f32x2{bflo(q.x), bfhi(q.x)};
        a23 += w2 * f32x2{bflo(q.y), bfhi(q.y)};
        a45 += w2 * f32x2{bflo(q.z), bfhi(q.z)};
        a67 += w2 * f32x2{bflo(q.w), bfhi(q.w)};
        den += wgt;
    }
    {   // self loop
        float ee = a_src[d * 4 + h] + ad;
        ee = fmaxf(ee, 0.2f * ee);
        const float wgt = __builtin_amdgcn_exp2f(ee);
        const uint4 q = *reinterpret_cast<const uint4*>(&hb[(size_t)d * HGAT_HC + c0]);
        const f32x2 w2 = {wgt, wgt};
        a01 += w2 * f32x2{bflo(q.x), bfhi(q.x)};
        a23 += w2 * f32x2{bflo(q.y), bfhi(q.y)};
        a45 += w2 * f32x2{bflo(q.z), bfhi(q.z)};
        a67 += w2 * f32x2{bflo(q.w), bfhi(q.w)};
        den += wgt;
    }

    const float inv = 1.0f / den;
    float v[8] = {a01.x * inv, a01.y * inv, a23.x * inv, a23.y * inv,
                  a45.x * inv, a45.y * inv, a67.x * inv, a67.y * inv};

    if (MODE == 0) {
        const float4 b0 = *reinterpret_cast<const float4*>(&bias[c0]);
        const float4 b1 = *reinterpret_cast<const float4*>(&bias[c0 + 4]);
        v[0] += b0.x; v[1] += b0.y; v[2] += b0.z; v[3] += b0.w;
        v[4] += b1.x; v[5] += b1.y; v[6] += b1.z; v[7] += b1.w;
        u16x8 u;
#pragma unroll
        for (int j = 0; j < 8; ++j) {
            const float r = v[j] > 0.f ? v[j] : expm1f(v[j]);
            u[j] = f2bf(r);
        }
        *reinterpret_cast<u16x8*>(&out[(size_t)d * HGAT_HC + c0]) = u;
    } else {
#pragma unroll
        for (int j = 0; j < 8; ++j) {
            v[j] += __shfl_xor(v[j], 8);
            v[j] += __shfl_xor(v[j], 16);
        }
        if (hl < 8) {
            const int c = hl * 8;
            const float4 b0 = *reinterpret_cast<const float4*>(&bias[c]);
            const float4 b1 = *reinterpret_cast<const float4*>(&bias[c + 4]);
            const float bb[8] = {b0.x, b0.y, b0.z, b0.w, b1.x, b1.y, b1.z, b1.w};
            u16x8 u;
#pragma unroll
            for (int j = 0; j < 8; ++j) {
                float r = 0.25f * v[j] + bb[j];
                r = r > 0.f ? r : expm1f(r);
                u[j] = f2bf(r);
            }
            *reinterpret_cast<u16x8*>(&out[(size_t)d * HGAT_C + c]) = u;
        }
    }
}

// ---------------------------------------------------------------------------
// Pool stage A + fused stage B (unchanged).
// ---------------------------------------------------------------------------
__device__ __forceinline__ int lower_bound_batch(
    const int* __restrict__ batch, int N, int key)
{
    int lo = 0, hi = N;
    while (lo < hi) {
        const int mid = (lo + hi) >> 1;
        if (batch[mid] < key) lo = mid + 1; else hi = mid;
    }
    return lo;
}

__global__ __launch_bounds__(256) void pool_partial_kernel(
    const ushort_t* __restrict__ hfin, const int* __restrict__ batch,
    float* __restrict__ partial, int N)
{
    const int g   = blockIdx.x >> 3;
    const int s   = blockIdx.x & 7;
    const int t   = threadIdx.x;
    const int c   = t & 63;
    const int sub = t >> 6;

    const int beg = lower_bound_batch(batch, N, g);
    const int end = lower_bound_batch(batch, N, g + 1);
    const int len = end - beg;
    const int sl  = (len + 7) >> 3;
    const int sb  = beg + s * sl;
    const int se  = sb + sl < end ? sb + sl : end;

    float acc = 0.f;
    for (int n = sb + sub; n < se; n += 4)
        acc += bf2f(hfin[(size_t)n * HGAT_C + c]);

    __shared__ float sm[256];
    sm[t] = acc;
    __syncthreads();
    if (sub == 0)
        partial[(size_t)(g * 8 + s) * HGAT_C + c] =
            sm[c] + sm[64 + c] + sm[128 + c] + sm[192 + c];
}

__global__ __launch_bounds__(64) void pool_final_fused_kernel(
    const float* __restrict__ partial, const int* __restrict__ batch,
    const float* __restrict__ Wa, const float* __restrict__ ba,
    float* __restrict__ out, int N)
{
    const int g = blockIdx.x;
    const int c = threadIdx.x;
    const int beg = lower_bound_batch(batch, N, g);
    const int end = lower_bound_batch(batch, N, g + 1);
    float s = 0.f;
#pragma unroll
    for (int k = 0; k < 8; ++k)
        s += partial[(size_t)(g * 8 + k) * HGAT_C + c];
    s /= fmaxf((float)(end - beg), 1.0f);

    __shared__ float pr[HGAT_C];
    pr[c] = s;
    __syncthreads();
    if (c < NACT) {
        float o = ba[c];
#pragma unroll
        for (int cc = 0; cc < HGAT_C; ++cc)
            o += pr[cc] * Wa[cc * NACT + c];
        out[g * NACT + c] = o;
    }
}

// ---------------------------------------------------------------------------
extern "C" void kernel_launch(void* const* d_in, const int* in_sizes, int n_in,
                              void* d_out, int out_size, void* d_ws, size_t ws_size,
                              hipStream_t stream)
{
    const float* x     = (const float*)d_in[0];
    const int*   ei    = (const int*)d_in[1];
    const int*   batch = (const int*)d_in[2];
    const float* W1    = (const float*)d_in[5];
    const float* as1   = (const float*)d_in[6];
    const float* ad1   = (const float*)d_in[7];
    const float* b1    = (const float*)d_in[8];
    const float* W2    = (const float*)d_in[9];
    const float* as2   = (const float*)d_in[10];
    const float* ad2   = (const float*)d_in[11];
    const float* b2    = (const float*)d_in[12];
    const float* Wa    = (const float*)d_in[13];
    const float* ba    = (const float*)d_in[14];

    const int N = in_sizes[0] / FIN;
    const int E = in_sizes[1] / 2;

    char* ws = (char*)d_ws;
    size_t off = 0;
    auto alloc = [&](size_t bytes) -> void* {
        void* p = ws + off;
        off += (bytes + 255) & ~(size_t)255;
        return p;
    };
    ushort_t* hb      = (ushort_t*)alloc((size_t)N * HGAT_HC * 2);
    ushort_t* hpost   = (ushort_t*)alloc((size_t)N * HGAT_HC * 2);
    ushort_t* Wt1     = (ushort_t*)alloc((size_t)FIN * HGAT_HC * 2);
    ushort_t* Wt2     = (ushort_t*)alloc((size_t)HGAT_HC * HGAT_HC * 2);
    ushort_t* attBt1  = (ushort_t*)alloc((size_t)16 * FIN * 2);
    ushort_t* attBt2  = (ushort_t*)alloc((size_t)16 * HGAT_HC * 2);
    float*    a_src   = (float*)alloc((size_t)N * 4 * 4);
    float*    a_dst   = (float*)alloc((size_t)N * 4 * 4);
    int*      rowptr  = (int*)alloc((size_t)(N + 1) * 4);
    int*      colsrc  = (int*)alloc((size_t)E * 4);
    int2*     staging = (int2*)alloc((size_t)E * 8);
    int*      bhist   = (int*)alloc((size_t)CNT_BLOCKS * 256 * 4);
    int*      boff    = (int*)alloc(257 * 4);
    int*      bcur    = (int*)alloc(256 * 4);
    float*    partial = (float*)alloc((size_t)NGRAPHS * 8 * HGAT_C * 4);
    ushort_t* hfin    = hpost;
    (void)ws_size; (void)n_in; (void)out_size;

    const int gemmBlocks = (N + 63) / 64;
    const int aggBlocks  = (N + 7) / 8;
    const int NBKT       = (N + 255) >> 8;
    const int SB         = (E + 4095) / 4096;     // scatter blocks
    const int prepTot    = FIN * HGAT_HC + HGAT_HC * HGAT_HC + (FIN + HGAT_HC) * 8;
    const int prepBlocks = (prepTot + 255) / 256;

    // ---------------- dispatch 1: edge histograms + prep ----------------
    bucket_count_prep_kernel<<<CNT_BLOCKS + prepBlocks, 256, 0, stream>>>(
        ei, bhist, W1, W2, as1, ad1, as2, ad2, Wt1, Wt2, attBt1, attBt2, E);

    // ---------------- dispatch 2: hist-sum + bucket scan ----------------
    bucket_scan_kernel<<<1, 256, 0, stream>>>(bhist, boff, bcur);

    // ---------------- dispatch 3: scatter || GEMM1 ----------------
    scatter_gemm1_kernel<<<SB + gemmBlocks, 256, 0, stream>>>(
        ei, bcur, staging, E, SB, x, Wt1, attBt1, hb, a_src, a_dst, N);

    // ---------------- dispatch 4: bucket fill ----------------
    bucket_fill_kernel<<<NBKT, 256, 0, stream>>>(
        staging, boff, rowptr, colsrc, N, E);

    // ---------------- layer 1 aggregate ----------------
    aggregate_csr_kernel<0><<<aggBlocks, 256, 0, stream>>>(
        rowptr, colsrc, hb, a_src, a_dst, b1, hpost, N);

    // ---------------- layer 2 ----------------
    gemm2_kernel<<<gemmBlocks, 256, 0, stream>>>(
        hpost, Wt2, attBt2, hb, a_src, a_dst, N);
    aggregate_csr_kernel<1><<<aggBlocks, 256, 0, stream>>>(
        rowptr, colsrc, hb, a_src, a_dst, b2, hfin, N);

    // ---------------- pool + final ----------------
    pool_partial_kernel<<<NGRAPHS * 8, 256, 0, stream>>>(hfin, batch, partial, N);
    pool_final_fused_kernel<<<NGRAPHS, 64, 0, stream>>>(
        partial, batch, Wa, ba, (float*)d_out, N);
}